// Round 3
// baseline (10277.216 us; speedup 1.0000x reference)
//
#include <hip/hip_runtime.h>
#include <hip/hip_bf16.h>

// VQ-VAE forward. R3: fp32 inputs/outputs (reference is pure float32),
// bf16 intermediates in workspace, fp32 accumulate. Direct VALU convs.

typedef unsigned short u16;
typedef unsigned int u32;

__device__ __forceinline__ float bf2f(u16 u) {
    union { u32 i; float f; } x; x.i = ((u32)u) << 16; return x.f;
}
__device__ __forceinline__ u16 f2bf(float f) {
    __hip_bfloat16 h = __float2bfloat16(f);
    return *reinterpret_cast<u16*>(&h);
}

__device__ __forceinline__ float lod(const float* p, size_t i) { return p[i]; }
__device__ __forceinline__ float lod(const u16*   p, size_t i) { return bf2f(p[i]); }
__device__ __forceinline__ void  sto(float* p, size_t i, float v) { p[i] = v; }
__device__ __forceinline__ void  sto(u16*   p, size_t i, float v) { p[i] = f2bf(v); }

// ---------------------------------------------------------------------------
// Direct conv. Block (32,8): 32x32 output tile, thread = 4 rows x CO_T couts.
// Weights staged fp32 in LDS as [ci][s][co] for broadcast reads.
// ---------------------------------------------------------------------------
template<int KH, int KW, int S, int CO_T, bool RELU, typename TX, typename TY>
__global__ __launch_bounds__(256) void conv_k(
    const TX* __restrict__ x, const float* __restrict__ w,
    const float* __restrict__ bias, TY* __restrict__ y,
    int N, int CIN, int COUT, int H, int W, int OH, int OW, int pad)
{
    constexpr int KHW = KH * KW;
    constexpr int CI_CHUNK = 32;
    __shared__ float wl[CI_CHUNK * KHW * CO_T];
    __shared__ float bl[CO_T];

    const int tx = threadIdx.x, ty = threadIdx.y;
    const int tid = ty * 32 + tx;

    const int coBlks = COUT / CO_T;
    int b = blockIdx.x;
    const int cb  = b % coBlks;  b /= coBlks;
    const int tilesX = OW >> 5;
    const int txi = b % tilesX;  b /= tilesX;
    const int tilesY = OH >> 5;
    const int tyi = b % tilesY;  b /= tilesY;
    const int n = b;

    const int ox  = (txi << 5) + tx;
    const int oy0 = (tyi << 5) + ty;

    if (tid < CO_T) bl[tid] = bias[cb * CO_T + tid];

    float acc[CO_T][4];
#pragma unroll
    for (int c = 0; c < CO_T; c++)
#pragma unroll
        for (int jj = 0; jj < 4; jj++) acc[c][jj] = 0.f;

    const int HW = H * W;
    for (int ci0 = 0; ci0 < CIN; ci0 += CI_CHUNK) {
        const int chunk = min(CI_CHUNK, CIN - ci0);
        __syncthreads();
        for (int i = tid; i < chunk * KHW * CO_T; i += 256) {
            int co = i % CO_T;
            int r  = i / CO_T;
            int s  = r % KHW;
            int ci = r / KHW;
            wl[(ci * KHW + s) * CO_T + co] =
                w[(size_t)((cb * CO_T + co) * CIN + (ci0 + ci)) * KHW + s];
        }
        __syncthreads();

        const TX* xb = x + (size_t)(n * CIN + ci0) * HW;

#pragma unroll
        for (int ky = 0; ky < KH; ky++) {
            int iy[4];
#pragma unroll
            for (int jj = 0; jj < 4; jj++) iy[jj] = (oy0 + 8 * jj) * S - pad + ky;
#pragma unroll
            for (int kx = 0; kx < KW; kx++) {
                const int ix = ox * S - pad + kx;
                const bool vx = (ix >= 0) & (ix < W);
                int off[4]; bool m[4];
#pragma unroll
                for (int jj = 0; jj < 4; jj++) {
                    m[jj] = vx & (iy[jj] >= 0) & (iy[jj] < H);
                    off[jj] = m[jj] ? (iy[jj] * W + ix) : 0;
                }
                const int s = ky * KW + kx;
                for (int ci = 0; ci < chunk; ci++) {
                    const TX* xc = xb + (size_t)ci * HW;
                    float xv[4];
#pragma unroll
                    for (int jj = 0; jj < 4; jj++) {
                        float v = lod(xc, off[jj]);
                        xv[jj] = m[jj] ? v : 0.f;
                    }
#pragma unroll
                    for (int co = 0; co < CO_T; co++) {
                        const float wv = wl[(ci * KHW + s) * CO_T + co];
#pragma unroll
                        for (int jj = 0; jj < 4; jj++) acc[co][jj] += xv[jj] * wv;
                    }
                }
            }
        }
    }

#pragma unroll
    for (int co = 0; co < CO_T; co++) {
        const int gco = cb * CO_T + co;
        TY* yp = y + (size_t)(n * COUT + gco) * OH * OW;
        const float bv = bl[co];
#pragma unroll
        for (int jj = 0; jj < 4; jj++) {
            float v = acc[co][jj] + bv;
            if (RELU) v = fmaxf(v, 0.f);
            sto(yp, (size_t)(oy0 + 8 * jj) * OW + ox, v);
        }
    }
}

// ---------------------------------------------------------------------------
// Transposed conv k=4 s=2 p=2 via 4 parity classes (blockIdx.y = py*2+px):
// y[2m+py, 2mx+px] = sum_{ci,a,b} w[ci,co,3-(py+2a),3-(px+2b)] *
//                    x[ci, m+py-1+a, mx+px-1+b]     (weights IOHW)
// ---------------------------------------------------------------------------
template<int CO_T, bool RELU, typename TX, typename TY>
__global__ __launch_bounds__(256) void deconv_k(
    const TX* __restrict__ x, const float* __restrict__ w,
    const float* __restrict__ bias, TY* __restrict__ y,
    int N, int CIN, int COUT, int H, int W)
{
    constexpr int CI_CHUNK = 32;
    __shared__ float wl[CI_CHUNK * 4 * CO_T];
    __shared__ float bl[CO_T];

    const int tx = threadIdx.x, ty = threadIdx.y;
    const int tid = ty * 32 + tx;
    const int py = blockIdx.y >> 1, px = blockIdx.y & 1;

    const int coBlks = COUT / CO_T;
    int b = blockIdx.x;
    const int cb  = b % coBlks;  b /= coBlks;
    const int tilesX = W >> 5;
    const int txi = b % tilesX;  b /= tilesX;
    const int tilesY = H >> 5;
    const int tyi = b % tilesY;  b /= tilesY;
    const int n = b;

    const int mx  = (txi << 5) + tx;
    const int my0 = (tyi << 5) + ty;

    if (tid < CO_T) bl[tid] = bias[cb * CO_T + tid];

    float acc[CO_T][4];
#pragma unroll
    for (int c = 0; c < CO_T; c++)
#pragma unroll
        for (int jj = 0; jj < 4; jj++) acc[c][jj] = 0.f;

    const int HW = H * W;
    for (int ci0 = 0; ci0 < CIN; ci0 += CI_CHUNK) {
        const int chunk = min(CI_CHUNK, CIN - ci0);
        __syncthreads();
        for (int i = tid; i < chunk * 4 * CO_T; i += 256) {
            int co = i % CO_T;
            int r  = i / CO_T;
            int ab = r % 4;
            int ci = r / 4;
            int a  = ab >> 1, bb = ab & 1;
            int ky = py + 2 * a, kx = px + 2 * bb;
            wl[(ci * 4 + ab) * CO_T + co] =
                w[(size_t)((ci0 + ci) * COUT + (cb * CO_T + co)) * 16
                  + (3 - ky) * 4 + (3 - kx)];
        }
        __syncthreads();

        const TX* xb = x + (size_t)(n * CIN + ci0) * HW;

#pragma unroll
        for (int a = 0; a < 2; a++) {
            int iy[4];
#pragma unroll
            for (int jj = 0; jj < 4; jj++) iy[jj] = (my0 + 8 * jj) + py - 1 + a;
#pragma unroll
            for (int bb = 0; bb < 2; bb++) {
                const int ix = mx + px - 1 + bb;
                const bool vx = (ix >= 0) & (ix < W);
                int off[4]; bool m[4];
#pragma unroll
                for (int jj = 0; jj < 4; jj++) {
                    m[jj] = vx & (iy[jj] >= 0) & (iy[jj] < H);
                    off[jj] = m[jj] ? (iy[jj] * W + ix) : 0;
                }
                const int s = a * 2 + bb;
                for (int ci = 0; ci < chunk; ci++) {
                    const TX* xc = xb + (size_t)ci * HW;
                    float xv[4];
#pragma unroll
                    for (int jj = 0; jj < 4; jj++) {
                        float v = lod(xc, off[jj]);
                        xv[jj] = m[jj] ? v : 0.f;
                    }
#pragma unroll
                    for (int co = 0; co < CO_T; co++) {
                        const float wv = wl[(ci * 4 + s) * CO_T + co];
#pragma unroll
                        for (int jj = 0; jj < 4; jj++) acc[co][jj] += xv[jj] * wv;
                    }
                }
            }
        }
    }

    const int OH = 2 * H, OW = 2 * W;
#pragma unroll
    for (int co = 0; co < CO_T; co++) {
        const int gco = cb * CO_T + co;
        TY* yp = y + (size_t)(n * COUT + gco) * OH * OW;
        const float bv = bl[co];
#pragma unroll
        for (int jj = 0; jj < 4; jj++) {
            float v = acc[co][jj] + bv;
            if (RELU) v = fmaxf(v, 0.f);
            const int oy = 2 * (my0 + 8 * jj) + py;
            const int ox = 2 * mx + px;
            sto(yp, (size_t)oy * OW + ox, v);
        }
    }
}

// ---------------------------------------------------------------------------
// VQ: 64-elem contiguous rows of z_e (fp32) vs 512x64 codebook.
// Distances with bf16 codebook in LDS (argmin robust: codebook ~ +-1/512);
// z_q row gathered from fp32 global codebook => exact reference bits.
// ---------------------------------------------------------------------------
__global__ __launch_bounds__(256) void vq_k(
    const float* __restrict__ ze, const float* __restrict__ cbk,
    float* __restrict__ zq)
{
    __shared__ u16 cl[512 * 64];
    __shared__ float cn[512];
    const int tid = threadIdx.x;

    for (int i = tid; i < 512 * 64; i += 256) cl[i] = f2bf(cbk[i]);
    for (int c = tid; c < 512; c += 256) {
        float s = 0.f;
        const float* row = cbk + c * 64;
        for (int i = 0; i < 64; i++) s += row[i] * row[i];
        cn[c] = s;
    }
    __syncthreads();

    const int vec = blockIdx.x * 256 + tid;     // 131072 vectors
    float v[64];
    const float4* vp = (const float4*)(ze + (size_t)vec * 64);
#pragma unroll
    for (int q = 0; q < 16; q++) {
        float4 u = vp[q];
        v[q * 4 + 0] = u.x; v[q * 4 + 1] = u.y;
        v[q * 4 + 2] = u.z; v[q * 4 + 3] = u.w;
    }

    float best = 3.4e38f; int bi = 0;
    for (int c = 0; c < 512; c++) {
        const u16* rp = cl + c * 64;
        float dot = 0.f;
#pragma unroll
        for (int i = 0; i < 64; i++) dot += v[i] * bf2f(rp[i]);
        const float s = cn[c] - 2.f * dot;
        if (s < best) { best = s; bi = c; }   // strict < == first-min (argmin)
    }

    float4* zp = (float4*)(zq + (size_t)vec * 64);
    const float4* sp = (const float4*)(cbk + (size_t)bi * 64);
#pragma unroll
    for (int q = 0; q < 16; q++) zp[q] = sp[q];   // exact fp32 codebook bits
}

// ---------------------------------------------------------------------------
extern "C" void kernel_launch(void* const* d_in, const int* in_sizes, int n_in,
                              void* d_out, int out_size, void* d_ws, size_t ws_size,
                              hipStream_t stream)
{
    (void)in_sizes; (void)n_in; (void)out_size; (void)ws_size;

    const float* x   = (const float*)d_in[0];
    const float* ew1 = (const float*)d_in[1];
    const float* eb1 = (const float*)d_in[2];
    const float* ew2 = (const float*)d_in[3];
    const float* eb2 = (const float*)d_in[4];
    const float* ew3 = (const float*)d_in[5];
    const float* eb3 = (const float*)d_in[6];
    const float* cbk = (const float*)d_in[7];
    const float* dw1 = (const float*)d_in[8];
    const float* db1 = (const float*)d_in[9];
    const float* dw2 = (const float*)d_in[10];
    const float* db2 = (const float*)d_in[11];
    const float* dw3 = (const float*)d_in[12];
    const float* db3 = (const float*)d_in[13];

    // ws: A = 32x128x128x128 bf16 (h1, reused as h_d2), B = 32x128x64x64 bf16
    u16* A = (u16*)d_ws;
    u16* B = A + (size_t)32 * 128 * 128 * 128;

    float* xr = (float*)d_out;                     // 32x3x256x256
    float* ze = xr + (size_t)32 * 3 * 256 * 256;   // 32x64x64x64
    float* zq = ze + (size_t)32 * 64 * 64 * 64;    // 32x64x64x64

    const dim3 blk(32, 8);

    // enc1: fp32 x -> bf16 A, k4 s2 p1, relu
    conv_k<4, 4, 2, 8, true><<<32 * 4 * 4 * 16, blk, 0, stream>>>(
        x, ew1, eb1, A, 32, 3, 128, 256, 256, 128, 128, 1);
    // enc2: bf16 A -> bf16 B, k4 s2 p1, relu
    conv_k<4, 4, 2, 8, true><<<32 * 2 * 2 * 16, blk, 0, stream>>>(
        A, ew2, eb2, B, 32, 128, 128, 128, 128, 64, 64, 1);
    // enc3: bf16 B -> fp32 z_e, k3 s1 p1
    conv_k<3, 3, 1, 8, false><<<32 * 2 * 2 * 8, blk, 0, stream>>>(
        B, ew3, eb3, ze, 32, 128, 64, 64, 64, 64, 64, 1);
    // VQ: fp32 z_e -> fp32 z_q (exact codebook rows)
    vq_k<<<512, 256, 0, stream>>>(ze, cbk, zq);
    // dec1: fp32 z_q -> bf16 B, k3 s1 p1, relu
    conv_k<3, 3, 1, 8, true><<<32 * 2 * 2 * 16, blk, 0, stream>>>(
        zq, dw1, db1, B, 32, 64, 128, 64, 64, 64, 64, 1);
    // dec2 (transposed): bf16 B -> bf16 A, relu
    deconv_k<8, true><<<dim3(32 * 2 * 2 * 16, 4), blk, 0, stream>>>(
        B, dw2, db2, A, 32, 128, 128, 64, 64);
    // dec3 (transposed): bf16 A -> fp32 x_recon
    deconv_k<3, false><<<dim3(32 * 4 * 4 * 1, 4), blk, 0, stream>>>(
        A, dw3, db3, xr, 32, 128, 3, 128, 128);
}

// Round 4
// 2434.536 us; speedup vs baseline: 4.2214x; 4.2214x over previous
//
#include <hip/hip_runtime.h>
#include <hip/hip_bf16.h>

// VQ-VAE forward. R4: MFMA implicit-GEMM for enc2/enc3/dec1/deconv2 via
// stride-1 plane decomposition; LDS-staged direct enc1; direct deconv3; VQ.
// fp32 in/out, bf16 intermediates + weights, fp32 accumulate.

typedef unsigned short u16;
typedef unsigned int u32;
typedef __attribute__((ext_vector_type(8))) short short8;
typedef __attribute__((ext_vector_type(4))) float f32x4;

__device__ __forceinline__ float bf2f(u16 u) {
    union { u32 i; float f; } x; x.i = ((u32)u) << 16; return x.f;
}
__device__ __forceinline__ u16 f2bf(float f) {
    __hip_bfloat16 h = __float2bfloat16(f);
    return *reinterpret_cast<u16*>(&h);
}
__device__ __forceinline__ float lod(const float* p, int i) { return p[i]; }
__device__ __forceinline__ float lod(const u16*   p, int i) { return bf2f(p[i]); }
__device__ __forceinline__ void sto(float* p, size_t i, float v) { p[i] = v; }
__device__ __forceinline__ void sto(u16*   p, size_t i, float v) { p[i] = f2bf(v); }

// ---------------------------------------------------------------------------
// Weight gathers into MFMA-friendly bf16 layout Wg[s][co][ci] (ci innermost).
// ---------------------------------------------------------------------------
__global__ void g_k3(const float* __restrict__ w, u16* __restrict__ wg,
                     int CIN, int COUT)   // OIHW k3: wg[(s*COUT+co)*CIN+ci]
{
    int idx = blockIdx.x * 256 + threadIdx.x;
    if (idx >= 9 * CIN * COUT) return;
    int ci = idx % CIN;
    int co = (idx / CIN) % COUT;
    int s  = idx / (CIN * COUT);
    wg[idx] = f2bf(w[(co * CIN + ci) * 9 + s]);
}

// enc2 k4s2 -> 4 input-parity planes, 2x2 taps. ky=(1-a)+2j, kx=(1-b)+2i.
__global__ void g_enc2(const float* __restrict__ w, u16* __restrict__ wg)
{
    int idx = blockIdx.x * 256 + threadIdx.x;   // p(4) s(4) co(128) ci(128)
    int ci = idx & 127, co = (idx >> 7) & 127, s = (idx >> 14) & 3, p = idx >> 16;
    int a = p >> 1, b = p & 1, j = s >> 1, i = s & 1;
    int ky = (1 - a) + 2 * j, kx = (1 - b) + 2 * i;
    wg[idx] = f2bf(w[((co << 7 | ci) << 4) + ky * 4 + kx]);
}

// deconv2 k4s2p2 -> 4 output parities, 2x2 taps, IOHW flipped weights.
__global__ void g_dec2(const float* __restrict__ w, u16* __restrict__ wg)
{
    int idx = blockIdx.x * 256 + threadIdx.x;   // p(4) s(4) co(128) ci(128)
    int ci = idx & 127, co = (idx >> 7) & 127, s = (idx >> 14) & 3, p = idx >> 16;
    int py = p >> 1, px = p & 1, j = s >> 1, i = s & 1;
    wg[idx] = f2bf(w[((ci << 7 | co) << 4) + (3 - (py + 2 * j)) * 4 + (3 - (px + 2 * i))]);
}

// ---------------------------------------------------------------------------
// enc1: k4 s2 p1, CIN=3, COUT=128, 256x256 -> 128x128, relu, writes output
// as 4 parity planes P[n][p][co][64][64] (p = (oy&1)*2 + (ox&1)).
// Block (16,16): out tile 32x32, thread = 2x2 quad, CO_T=16.
// ---------------------------------------------------------------------------
__global__ __launch_bounds__(256) void enc1_k(
    const float* __restrict__ x, const float* __restrict__ w,
    const float* __restrict__ bias, u16* __restrict__ P)
{
    __shared__ float xin[3 * 67 * 68];
    __shared__ float wl[3 * 16 * 16];

    const int tx = threadIdx.x, ty = threadIdx.y;
    const int tid = ty * 16 + tx;

    int b = blockIdx.x;
    const int cob = b & 7;  b >>= 3;
    const int TXi = b & 3;  b >>= 2;
    const int TYi = b & 3;  b >>= 2;
    const int n = b;

    // stage weights: wl[ci][s][co]
    for (int i = tid; i < 3 * 16 * 16; i += 256) {
        int co = i & 15, s = (i >> 4) & 15, ci = i >> 8;
        wl[i] = w[((cob * 16 + co) * 3 + ci) * 16 + s];
    }
    // stage input region 67x67x3 at (64*TYi-1, 64*TXi-1)
    const int RY0 = 64 * TYi - 1, RX0 = 64 * TXi - 1;
    for (int it = 0; it < 53; it++) {
        int idx = it * 256 + tid;
        if (idx < 3 * 67 * 67) {
            int col = idx % 67;
            int row = (idx / 67) % 67;
            int ci  = idx / (67 * 67);
            int gr = RY0 + row, gc = RX0 + col;
            float v = 0.f;
            if (gr >= 0 && gr < 256 && gc >= 0 && gc < 256)
                v = x[((n * 3 + ci) * 256 + gr) * 256 + gc];
            xin[(ci * 67 + row) * 68 + col] = v;
        }
    }
    __syncthreads();

    float acc[16][4];
#pragma unroll
    for (int c = 0; c < 16; c++)
#pragma unroll
        for (int q = 0; q < 4; q++) acc[c][q] = 0.f;

#pragma unroll
    for (int ky = 0; ky < 4; ky++)
#pragma unroll
        for (int kx = 0; kx < 4; kx++)
#pragma unroll
            for (int ci = 0; ci < 3; ci++) {
                float xv[4];
#pragma unroll
                for (int qy = 0; qy < 2; qy++)
#pragma unroll
                    for (int qx = 0; qx < 2; qx++) {
                        int iyl = 2 * (2 * ty + qy) + ky;
                        int ixl = 2 * (2 * tx + qx) + kx;
                        xv[qy * 2 + qx] = xin[(ci * 67 + iyl) * 68 + ixl];
                    }
                const float* wrow = &wl[(ci * 16 + (ky * 4 + kx)) * 16];
#pragma unroll
                for (int co = 0; co < 16; co++) {
                    float wv = wrow[co];
#pragma unroll
                    for (int q = 0; q < 4; q++) acc[co][q] += xv[q] * wv;
                }
            }

    // store to parity planes
#pragma unroll
    for (int co = 0; co < 16; co++) {
        const int cog = cob * 16 + co;
        const float bv = bias[cog];
#pragma unroll
        for (int qy = 0; qy < 2; qy++)
#pragma unroll
            for (int qx = 0; qx < 2; qx++) {
                float v = fmaxf(acc[co][qy * 2 + qx] + bv, 0.f);
                int p = qy * 2 + qx;
                size_t addr = (((size_t)(n * 4 + p) * 128 + cog) * 64
                               + (TYi * 16 + ty)) * 64 + (TXi * 16 + tx);
                P[addr] = f2bf(v);
            }
    }
}

// ---------------------------------------------------------------------------
// Unified stride-1 MFMA conv on 64x64 planes.
// J x I taps; NP input planes (enc2=4); DEC: 4 output parities (blockIdx.y),
// strided store to 128x128. Block 256 thr = 4 waves; out tile 64co x 128px
// (2 rows x 64 cols); per wave: co-tile 16 x 8 n-tiles.
// Input staged LDS [4r][68c][ci pad 34] bf16. Weights pre-gathered bf16
// Wg[(p|pc)][s][co][ci]. fp32 bias, fp32 accumulate.
// ---------------------------------------------------------------------------
template<int J, int I, int NP, bool DEC, bool RELU, typename TX, typename TY>
__global__ __launch_bounds__(256) void conv_mx(
    const TX* __restrict__ x, const u16* __restrict__ wg,
    const float* __restrict__ bias, TY* __restrict__ y,
    int CIN, int cobN)
{
    __shared__ u16 XL[4 * 68 * 34];

    const int tid = threadIdx.x;
    const int l = tid & 63, wv = tid >> 6;
    const int kg = l >> 4, ln = l & 15;

    int b = blockIdx.x;
    const int cobi = b % cobN;  b /= cobN;
    const int tile = b & 31;    b >>= 5;
    const int n = b;
    const int OY0 = tile * 2;
    const int COUT = cobN * 64;
    const int pc = DEC ? blockIdx.y : 0;

    f32x4 acc[8];
#pragma unroll
    for (int t = 0; t < 8; t++) acc[t] = (f32x4){0.f, 0.f, 0.f, 0.f};

    const TX* xn = x + (size_t)n * NP * CIN * 4096;
    const u32* XL32 = (const u32*)XL;

    for (int p = 0; p < NP; p++) {
        int dy0, dx0;
        const u16* wgp;
        if (DEC) {
            dy0 = (pc >> 1) - 1; dx0 = (pc & 1) - 1;
            wgp = wg + (size_t)pc * J * I * COUT * CIN;
        } else if (NP == 4) {
            dy0 = -(p >> 1); dx0 = -(p & 1);
            wgp = wg + (size_t)p * J * I * COUT * CIN;
        } else {
            dy0 = -1; dx0 = -1; wgp = wg;
        }
        const TX* xp = xn + (size_t)p * CIN * 4096;

        for (int ci0 = 0; ci0 < CIN; ci0 += 32) {
            __syncthreads();
            // stage 4 rows x 68 cols x 32 ci (rows OY0-1..OY0+2, cols -1..66)
#pragma unroll
            for (int it = 0; it < 17; it++) {
                int idx = it * 256 + tid;
                int cp = idx % 34;
                int rest = idx / 34;
                int ci = rest & 31;
                int r = rest >> 5;
                int gr = OY0 - 1 + r;
                const TX* src = xp + (size_t)(ci0 + ci) * 4096 + gr * 64;
                int gc0 = 2 * cp - 1;
                bool rok = (gr >= 0) & (gr < 64);
                float v0 = (rok && gc0 >= 0 && gc0 < 64) ? lod(src, gc0) : 0.f;
                float v1 = (rok && gc0 + 1 < 64) ? lod(src, gc0 + 1) : 0.f;
                int base = (r * 68 + 2 * cp) * 34 + ci;
                XL[base] = f2bf(v0);
                XL[base + 34] = f2bf(v1);
            }
            __syncthreads();

            // weight fragments: lane: co = cobi*64 + wv*16 + ln, k = ci0+8kg+j
            short8 wf[J * I];
            const int co_l = cobi * 64 + wv * 16 + ln;
#pragma unroll
            for (int s = 0; s < J * I; s++)
                wf[s] = *(const short8*)(wgp + (size_t)(s * COUT + co_l) * CIN
                                         + ci0 + 8 * kg);

#pragma unroll
            for (int j = 0; j < J; j++)
#pragma unroll
                for (int i = 0; i < I; i++) {
                    const int s = j * I + i;
#pragma unroll
                    for (int t = 0; t < 8; t++) {
                        int r = (t >> 2) + dy0 + 1 + j;
                        int col = (t & 3) * 16 + ln + dx0 + 1 + i;
                        int bu = (r * 68 + col) * 17 + 4 * kg;
                        union { u32 d[4]; short8 v; } bf;
                        bf.d[0] = XL32[bu];     bf.d[1] = XL32[bu + 1];
                        bf.d[2] = XL32[bu + 2]; bf.d[3] = XL32[bu + 3];
                        acc[t] = __builtin_amdgcn_mfma_f32_16x16x32_bf16(
                            wf[s], bf.v, acc[t], 0, 0, 0);
                    }
                }
        }
    }

    // epilogue: D elem r -> co = cobi*64 + wv*16 + 4*kg + r, px col = ln
#pragma unroll
    for (int t = 0; t < 8; t++) {
        const int oy = OY0 + (t >> 2);
        const int ox = (t & 3) * 16 + ln;
#pragma unroll
        for (int r = 0; r < 4; r++) {
            const int co = cobi * 64 + wv * 16 + 4 * kg + r;
            float v = acc[t][r] + bias[co];
            if (RELU) v = fmaxf(v, 0.f);
            if (DEC)
                sto(y, ((size_t)(n * COUT + co) * 128 + 2 * oy + (pc >> 1)) * 128
                        + 2 * ox + (pc & 1), v);
            else
                sto(y, ((size_t)(n * COUT + co) * 64 + oy) * 64 + ox, v);
        }
    }
}

// ---------------------------------------------------------------------------
// Direct transposed conv (deconv3, COUT=3). From R3 (validated).
// ---------------------------------------------------------------------------
template<int CO_T, bool RELU, typename TX, typename TY>
__global__ __launch_bounds__(256) void deconv_k(
    const TX* __restrict__ x, const float* __restrict__ w,
    const float* __restrict__ bias, TY* __restrict__ y,
    int N, int CIN, int COUT, int H, int W)
{
    constexpr int CI_CHUNK = 32;
    __shared__ float wl[CI_CHUNK * 4 * CO_T];
    __shared__ float bl[CO_T];

    const int tx = threadIdx.x, ty = threadIdx.y;
    const int tid = ty * 32 + tx;
    const int py = blockIdx.y >> 1, px = blockIdx.y & 1;

    const int coBlks = COUT / CO_T;
    int b = blockIdx.x;
    const int cb  = b % coBlks;  b /= coBlks;
    const int tilesX = W >> 5;
    const int txi = b % tilesX;  b /= tilesX;
    const int tilesY = H >> 5;
    const int tyi = b % tilesY;  b /= tilesY;
    const int n = b;

    const int mx  = (txi << 5) + tx;
    const int my0 = (tyi << 5) + ty;

    if (tid < CO_T) bl[tid] = bias[cb * CO_T + tid];

    float acc[CO_T][4];
#pragma unroll
    for (int c = 0; c < CO_T; c++)
#pragma unroll
        for (int jj = 0; jj < 4; jj++) acc[c][jj] = 0.f;

    const int HW = H * W;
    for (int ci0 = 0; ci0 < CIN; ci0 += CI_CHUNK) {
        const int chunk = min(CI_CHUNK, CIN - ci0);
        __syncthreads();
        for (int i = tid; i < chunk * 4 * CO_T; i += 256) {
            int co = i % CO_T;
            int rr = i / CO_T;
            int ab = rr % 4;
            int ci = rr / 4;
            int a  = ab >> 1, bb = ab & 1;
            int ky = py + 2 * a, kx = px + 2 * bb;
            wl[(ci * 4 + ab) * CO_T + co] =
                w[(size_t)((ci0 + ci) * COUT + (cb * CO_T + co)) * 16
                  + (3 - ky) * 4 + (3 - kx)];
        }
        __syncthreads();

        const TX* xb = x + (size_t)(n * CIN + ci0) * HW;

#pragma unroll
        for (int a = 0; a < 2; a++) {
            int iy[4];
#pragma unroll
            for (int jj = 0; jj < 4; jj++) iy[jj] = (my0 + 8 * jj) + py - 1 + a;
#pragma unroll
            for (int bb = 0; bb < 2; bb++) {
                const int ix = mx + px - 1 + bb;
                const bool vx = (ix >= 0) & (ix < W);
                int off[4]; bool m[4];
#pragma unroll
                for (int jj = 0; jj < 4; jj++) {
                    m[jj] = vx & (iy[jj] >= 0) & (iy[jj] < H);
                    off[jj] = m[jj] ? (iy[jj] * W + ix) : 0;
                }
                const int s = a * 2 + bb;
                for (int ci = 0; ci < chunk; ci++) {
                    const TX* xc = xb + (size_t)ci * HW;
                    float xv[4];
#pragma unroll
                    for (int jj = 0; jj < 4; jj++) {
                        float v = lod(xc, off[jj]);
                        xv[jj] = m[jj] ? v : 0.f;
                    }
#pragma unroll
                    for (int co = 0; co < CO_T; co++) {
                        const float wvv = wl[(ci * 4 + s) * CO_T + co];
#pragma unroll
                        for (int jj = 0; jj < 4; jj++) acc[co][jj] += xv[jj] * wvv;
                    }
                }
            }
        }
    }

    const int OH = 2 * H, OW = 2 * W;
#pragma unroll
    for (int co = 0; co < CO_T; co++) {
        const int gco = cb * CO_T + co;
        TY* yp = y + (size_t)(n * COUT + gco) * OH * OW;
        const float bv = bl[co];
#pragma unroll
        for (int jj = 0; jj < 4; jj++) {
            float v = acc[co][jj] + bv;
            if (RELU) v = fmaxf(v, 0.f);
            const int oy = 2 * (my0 + 8 * jj) + py;
            const int ox = 2 * mx + px;
            sto(yp, (size_t)oy * OW + ox, v);
        }
    }
}

// ---------------------------------------------------------------------------
// VQ (from R3, validated): bf16 codebook distances in LDS, exact fp32 rows out.
// ---------------------------------------------------------------------------
__global__ __launch_bounds__(256) void vq_k(
    const float* __restrict__ ze, const float* __restrict__ cbk,
    float* __restrict__ zq)
{
    __shared__ u16 cl[512 * 64];
    __shared__ float cn[512];
    const int tid = threadIdx.x;

    for (int i = tid; i < 512 * 64; i += 256) cl[i] = f2bf(cbk[i]);
    for (int c = tid; c < 512; c += 256) {
        float s = 0.f;
        const float* row = cbk + c * 64;
        for (int i = 0; i < 64; i++) s += row[i] * row[i];
        cn[c] = s;
    }
    __syncthreads();

    const int vec = blockIdx.x * 256 + tid;
    float v[64];
    const float4* vp = (const float4*)(ze + (size_t)vec * 64);
#pragma unroll
    for (int q = 0; q < 16; q++) {
        float4 u = vp[q];
        v[q * 4 + 0] = u.x; v[q * 4 + 1] = u.y;
        v[q * 4 + 2] = u.z; v[q * 4 + 3] = u.w;
    }

    float best = 3.4e38f; int bi = 0;
    for (int c = 0; c < 512; c++) {
        const u16* rp = cl + c * 64;
        float dot = 0.f;
#pragma unroll
        for (int i = 0; i < 64; i++) dot += v[i] * bf2f(rp[i]);
        const float s = cn[c] - 2.f * dot;
        if (s < best) { best = s; bi = c; }
    }

    float4* zp = (float4*)(zq + (size_t)vec * 64);
    const float4* sp = (const float4*)(cbk + (size_t)bi * 64);
#pragma unroll
    for (int q = 0; q < 16; q++) zp[q] = sp[q];
}

// ---------------------------------------------------------------------------
extern "C" void kernel_launch(void* const* d_in, const int* in_sizes, int n_in,
                              void* d_out, int out_size, void* d_ws, size_t ws_size,
                              hipStream_t stream)
{
    (void)in_sizes; (void)n_in; (void)out_size; (void)ws_size;

    const float* x   = (const float*)d_in[0];
    const float* ew1 = (const float*)d_in[1];
    const float* eb1 = (const float*)d_in[2];
    const float* ew2 = (const float*)d_in[3];
    const float* eb2 = (const float*)d_in[4];
    const float* ew3 = (const float*)d_in[5];
    const float* eb3 = (const float*)d_in[6];
    const float* cbk = (const float*)d_in[7];
    const float* dw1 = (const float*)d_in[8];
    const float* db1 = (const float*)d_in[9];
    const float* dw2 = (const float*)d_in[10];
    const float* db2 = (const float*)d_in[11];
    const float* dw3 = (const float*)d_in[12];
    const float* db3 = (const float*)d_in[13];

    // workspace layout (bytes):
    //   P: parity planes of h1, 32*4*128*64*64 u16 = 134,217,728  (aliased by A)
    //   B: 32*128*64*64 u16 = 33,554,432
    //   Wg2/Wg3/Wg4/Wg5: gathered bf16 weights
    u16* P = (u16*)d_ws;
    u16* A = P;                                       // deconv2 out (P dead then)
    u16* B = (u16*)((char*)d_ws + 134217728);
    u16* Wg2 = (u16*)((char*)d_ws + 167772160);       // 4*4*128*128
    u16* Wg3 = Wg2 + 262144;                          // 9*64*128
    u16* Wg4 = Wg3 + 73728;                           // 9*128*64
    u16* Wg5 = Wg4 + 73728;                           // 4*4*128*128

    float* xr = (float*)d_out;
    float* ze = xr + (size_t)32 * 3 * 256 * 256;
    float* zq = ze + (size_t)32 * 64 * 64 * 64;

    // weight gathers (tiny)
    g_enc2<<<1024, 256, 0, stream>>>(ew2, Wg2);
    g_k3<<<288, 256, 0, stream>>>(ew3, Wg3, 128, 64);
    g_k3<<<288, 256, 0, stream>>>(dw1, Wg4, 64, 128);
    g_dec2<<<1024, 256, 0, stream>>>(dw2, Wg5);

    // enc1: fp32 x -> parity planes P, relu
    enc1_k<<<4096, dim3(16, 16), 0, stream>>>(x, ew1, eb1, P);

    // enc2: 4 planes k2 -> B (relu). grid = cobN*32tiles*32n
    conv_mx<2, 2, 4, false, true, u16, u16><<<2 * 32 * 32, 256, 0, stream>>>(
        P, Wg2, eb2, B, 128, 2);
    // enc3: k3 -> ze (fp32, no relu)
    conv_mx<3, 3, 1, false, false, u16, float><<<1 * 32 * 32, 256, 0, stream>>>(
        B, Wg3, eb3, ze, 128, 1);
    // VQ
    vq_k<<<512, 256, 0, stream>>>(ze, cbk, zq);
    // dec1: k3, fp32 zq -> B (relu)
    conv_mx<3, 3, 1, false, true, float, u16><<<2 * 32 * 32, 256, 0, stream>>>(
        zq, Wg4, db1, B, 64, 2);
    // deconv2: k2 x 4 output parities -> A (relu)
    conv_mx<2, 2, 1, true, true, u16, u16><<<dim3(2 * 32 * 32, 4), 256, 0, stream>>>(
        B, Wg5, db2, A, 128, 2);
    // deconv3: direct -> x_recon
    deconv_k<3, false, u16, float><<<dim3(32 * 4 * 4 * 1, 4), dim3(32, 8), 0, stream>>>(
        A, dw3, db3, xr, 32, 128, 3, 128, 128);
}

// Round 5
// 1750.477 us; speedup vs baseline: 5.8711x; 1.3908x over previous
//
#include <hip/hip_runtime.h>
#include <hip/hip_bf16.h>

// VQ-VAE forward. R5: deconv3 -> MFMA implicit GEMM (channel-last input,
// fused parities, input fetched once); VQ -> MFMA GEMM + shfl argmin.
// fp32 in/out, bf16 intermediates + weights, fp32 accumulate.

typedef unsigned short u16;
typedef unsigned int u32;
typedef unsigned long long u64;
typedef __attribute__((ext_vector_type(8))) short short8;
typedef __attribute__((ext_vector_type(4))) float f32x4;

__device__ __forceinline__ float bf2f(u16 u) {
    union { u32 i; float f; } x; x.i = ((u32)u) << 16; return x.f;
}
__device__ __forceinline__ u16 f2bf(float f) {
    __hip_bfloat16 h = __float2bfloat16(f);
    return *reinterpret_cast<u16*>(&h);
}
__device__ __forceinline__ float lod(const float* p, int i) { return p[i]; }
__device__ __forceinline__ float lod(const u16*   p, int i) { return bf2f(p[i]); }
__device__ __forceinline__ void sto(float* p, size_t i, float v) { p[i] = v; }
__device__ __forceinline__ void sto(u16*   p, size_t i, float v) { p[i] = f2bf(v); }

// ---------------------------------------------------------------------------
// Weight gathers into MFMA layouts (bf16, ci innermost).
// ---------------------------------------------------------------------------
__global__ void g_k3(const float* __restrict__ w, u16* __restrict__ wg,
                     int CIN, int COUT)   // OIHW k3: wg[(s*COUT+co)*CIN+ci]
{
    int idx = blockIdx.x * 256 + threadIdx.x;
    if (idx >= 9 * CIN * COUT) return;
    int ci = idx % CIN;
    int co = (idx / CIN) % COUT;
    int s  = idx / (CIN * COUT);
    wg[idx] = f2bf(w[(co * CIN + ci) * 9 + s]);
}

// enc2 k4s2 -> 4 input-parity planes, 2x2 taps. ky=(1-a)+2j, kx=(1-b)+2i.
__global__ void g_enc2(const float* __restrict__ w, u16* __restrict__ wg)
{
    int idx = blockIdx.x * 256 + threadIdx.x;   // p(4) s(4) co(128) ci(128)
    int ci = idx & 127, co = (idx >> 7) & 127, s = (idx >> 14) & 3, p = idx >> 16;
    int a = p >> 1, b = p & 1, j = s >> 1, i = s & 1;
    int ky = (1 - a) + 2 * j, kx = (1 - b) + 2 * i;
    wg[idx] = f2bf(w[((co << 7 | ci) << 4) + ky * 4 + kx]);
}

// deconv2 k4s2p2 -> 4 output parities, 2x2 taps, IOHW flipped weights.
__global__ void g_dec2(const float* __restrict__ w, u16* __restrict__ wg)
{
    int idx = blockIdx.x * 256 + threadIdx.x;   // p(4) s(4) co(128) ci(128)
    int ci = idx & 127, co = (idx >> 7) & 127, s = (idx >> 14) & 3, p = idx >> 16;
    int py = p >> 1, px = p & 1, j = s >> 1, i = s & 1;
    wg[idx] = f2bf(w[((ci << 7 | co) << 4) + (3 - (py + 2 * j)) * 4 + (3 - (px + 2 * i))]);
}

// deconv3 (CIN=128, COUT=3 padded to 16): wg[((p*4+s)*16+co)*128+ci]
__global__ void g_dec3(const float* __restrict__ w, u16* __restrict__ wg)
{
    int idx = blockIdx.x * 256 + threadIdx.x;   // 4*4*16*128 = 32768
    if (idx >= 32768) return;
    int ci = idx & 127;
    int co = (idx >> 7) & 15;
    int s  = (idx >> 11) & 3;
    int p  = idx >> 13;
    int a = s >> 1, b2 = s & 1, py = p >> 1, px = p & 1;
    float v = 0.f;
    if (co < 3) v = w[(ci * 3 + co) * 16 + (3 - (py + 2 * a)) * 4 + (3 - (px + 2 * b2))];
    wg[idx] = f2bf(v);
}

// codebook: bf16 copy + norms
__global__ void g_cbk(const float* __restrict__ cbk, u16* __restrict__ cb,
                      float* __restrict__ cn)
{
    int idx = blockIdx.x * 256 + threadIdx.x;   // 32768
    if (idx >= 32768) return;
    cb[idx] = f2bf(cbk[idx]);
    if (idx < 512) {
        float s = 0.f;
        const float* r = cbk + idx * 64;
        for (int i = 0; i < 64; i++) s += r[i] * r[i];
        cn[idx] = s;
    }
}

// ---------------------------------------------------------------------------
// enc1: k4 s2 p1, CIN=3, 256x256 -> 128x128, relu, output as 4 parity planes
// P[n][p][co][64][64]. Block (16,16): 32x32 out tile, thread 2x2 quad, CO_T=16.
// ---------------------------------------------------------------------------
__global__ __launch_bounds__(256) void enc1_k(
    const float* __restrict__ x, const float* __restrict__ w,
    const float* __restrict__ bias, u16* __restrict__ P)
{
    __shared__ float xin[3 * 67 * 68];
    __shared__ float wl[3 * 16 * 16];

    const int tx = threadIdx.x, ty = threadIdx.y;
    const int tid = ty * 16 + tx;

    int b = blockIdx.x;
    const int cob = b & 7;  b >>= 3;
    const int TXi = b & 3;  b >>= 2;
    const int TYi = b & 3;  b >>= 2;
    const int n = b;

    for (int i = tid; i < 3 * 16 * 16; i += 256) {
        int co = i & 15, s = (i >> 4) & 15, ci = i >> 8;
        wl[i] = w[((cob * 16 + co) * 3 + ci) * 16 + s];
    }
    const int RY0 = 64 * TYi - 1, RX0 = 64 * TXi - 1;
    for (int it = 0; it < 53; it++) {
        int idx = it * 256 + tid;
        if (idx < 3 * 67 * 67) {
            int col = idx % 67;
            int row = (idx / 67) % 67;
            int ci  = idx / (67 * 67);
            int gr = RY0 + row, gc = RX0 + col;
            float v = 0.f;
            if (gr >= 0 && gr < 256 && gc >= 0 && gc < 256)
                v = x[((n * 3 + ci) * 256 + gr) * 256 + gc];
            xin[(ci * 67 + row) * 68 + col] = v;
        }
    }
    __syncthreads();

    float acc[16][4];
#pragma unroll
    for (int c = 0; c < 16; c++)
#pragma unroll
        for (int q = 0; q < 4; q++) acc[c][q] = 0.f;

#pragma unroll
    for (int ky = 0; ky < 4; ky++)
#pragma unroll
        for (int kx = 0; kx < 4; kx++)
#pragma unroll
            for (int ci = 0; ci < 3; ci++) {
                float xv[4];
#pragma unroll
                for (int qy = 0; qy < 2; qy++)
#pragma unroll
                    for (int qx = 0; qx < 2; qx++) {
                        int iyl = 2 * (2 * ty + qy) + ky;
                        int ixl = 2 * (2 * tx + qx) + kx;
                        xv[qy * 2 + qx] = xin[(ci * 67 + iyl) * 68 + ixl];
                    }
                const float* wrow = &wl[(ci * 16 + (ky * 4 + kx)) * 16];
#pragma unroll
                for (int co = 0; co < 16; co++) {
                    float wv = wrow[co];
#pragma unroll
                    for (int q = 0; q < 4; q++) acc[co][q] += xv[q] * wv;
                }
            }

#pragma unroll
    for (int co = 0; co < 16; co++) {
        const int cog = cob * 16 + co;
        const float bv = bias[cog];
#pragma unroll
        for (int qy = 0; qy < 2; qy++)
#pragma unroll
            for (int qx = 0; qx < 2; qx++) {
                float v = fmaxf(acc[co][qy * 2 + qx] + bv, 0.f);
                int p = qy * 2 + qx;
                size_t addr = (((size_t)(n * 4 + p) * 128 + cog) * 64
                               + (TYi * 16 + ty)) * 64 + (TXi * 16 + tx);
                P[addr] = f2bf(v);
            }
    }
}

// ---------------------------------------------------------------------------
// Unified stride-1 MFMA conv on 64x64 planes (enc2/enc3/dec1/deconv2).
// CL: deconv2 stores channel-last A2[n][y][x][co] (packed 4xbf16 = 8B).
// ---------------------------------------------------------------------------
template<int J, int I, int NP, bool DEC, bool CL, bool RELU, typename TX, typename TY>
__global__ __launch_bounds__(256) void conv_mx(
    const TX* __restrict__ x, const u16* __restrict__ wg,
    const float* __restrict__ bias, TY* __restrict__ y,
    int CIN, int cobN)
{
    __shared__ u16 XL[4 * 68 * 34];

    const int tid = threadIdx.x;
    const int l = tid & 63, wv = tid >> 6;
    const int kg = l >> 4, ln = l & 15;

    int b = blockIdx.x;
    const int cobi = b % cobN;  b /= cobN;
    const int tile = b & 31;    b >>= 5;
    const int n = b;
    const int OY0 = tile * 2;
    const int COUT = cobN * 64;
    const int pc = DEC ? blockIdx.y : 0;

    f32x4 acc[8];
#pragma unroll
    for (int t = 0; t < 8; t++) acc[t] = (f32x4){0.f, 0.f, 0.f, 0.f};

    const TX* xn = x + (size_t)n * NP * CIN * 4096;
    const u32* XL32 = (const u32*)XL;

    for (int p = 0; p < NP; p++) {
        int dy0, dx0;
        const u16* wgp;
        if (DEC) {
            dy0 = (pc >> 1) - 1; dx0 = (pc & 1) - 1;
            wgp = wg + (size_t)pc * J * I * COUT * CIN;
        } else if (NP == 4) {
            dy0 = -(p >> 1); dx0 = -(p & 1);
            wgp = wg + (size_t)p * J * I * COUT * CIN;
        } else {
            dy0 = -1; dx0 = -1; wgp = wg;
        }
        const TX* xp = xn + (size_t)p * CIN * 4096;

        for (int ci0 = 0; ci0 < CIN; ci0 += 32) {
            __syncthreads();
#pragma unroll
            for (int it = 0; it < 17; it++) {
                int idx = it * 256 + tid;
                int cp = idx % 34;
                int rest = idx / 34;
                int ci = rest & 31;
                int r = rest >> 5;
                int gr = OY0 - 1 + r;
                const TX* src = xp + (size_t)(ci0 + ci) * 4096 + gr * 64;
                int gc0 = 2 * cp - 1;
                bool rok = (gr >= 0) & (gr < 64);
                float v0 = (rok && gc0 >= 0 && gc0 < 64) ? lod(src, gc0) : 0.f;
                float v1 = (rok && gc0 + 1 < 64) ? lod(src, gc0 + 1) : 0.f;
                int base = (r * 68 + 2 * cp) * 34 + ci;
                XL[base] = f2bf(v0);
                XL[base + 34] = f2bf(v1);
            }
            __syncthreads();

            short8 wf[J * I];
            const int co_l = cobi * 64 + wv * 16 + ln;
#pragma unroll
            for (int s = 0; s < J * I; s++)
                wf[s] = *(const short8*)(wgp + (size_t)(s * COUT + co_l) * CIN
                                         + ci0 + 8 * kg);

#pragma unroll
            for (int j = 0; j < J; j++)
#pragma unroll
                for (int i = 0; i < I; i++) {
                    const int s = j * I + i;
#pragma unroll
                    for (int t = 0; t < 8; t++) {
                        int r = (t >> 2) + dy0 + 1 + j;
                        int col = (t & 3) * 16 + ln + dx0 + 1 + i;
                        int bu = (r * 68 + col) * 17 + 4 * kg;
                        union { u32 d[4]; short8 v; } bf;
                        bf.d[0] = XL32[bu];     bf.d[1] = XL32[bu + 1];
                        bf.d[2] = XL32[bu + 2]; bf.d[3] = XL32[bu + 3];
                        acc[t] = __builtin_amdgcn_mfma_f32_16x16x32_bf16(
                            wf[s], bf.v, acc[t], 0, 0, 0);
                    }
                }
        }
    }

#pragma unroll
    for (int t = 0; t < 8; t++) {
        const int oy = OY0 + (t >> 2);
        const int ox = (t & 3) * 16 + ln;
        const int cobase = cobi * 64 + wv * 16 + 4 * kg;
        if (DEC && CL) {
            // channel-last packed store: 4 consecutive couts = 8 bytes
            u16 pk[4];
#pragma unroll
            for (int r = 0; r < 4; r++) {
                float v = acc[t][r] + bias[cobase + r];
                if (RELU) v = fmaxf(v, 0.f);
                pk[r] = f2bf(v);
            }
            const int OYy = 2 * oy + (pc >> 1), OXx = 2 * ox + (pc & 1);
            *(u64*)((u16*)y + ((size_t)(n * 128 + OYy) * 128 + OXx) * COUT + cobase)
                = *(const u64*)pk;
        } else {
#pragma unroll
            for (int r = 0; r < 4; r++) {
                const int co = cobase + r;
                float v = acc[t][r] + bias[co];
                if (RELU) v = fmaxf(v, 0.f);
                if (DEC)
                    sto(y, ((size_t)(n * COUT + co) * 128 + 2 * oy + (pc >> 1)) * 128
                            + 2 * ox + (pc & 1), v);
                else
                    sto(y, ((size_t)(n * COUT + co) * 64 + oy) * 64 + ox, v);
            }
        }
    }
}

// ---------------------------------------------------------------------------
// deconv3 via MFMA: input A2[n][y][x][128] bf16 (channel-last), all 4
// parities fused -> input fetched once. Wave: 16 m-cols x 8 m-rows.
// B-frag = one 16B global load; weights from padded table (co 3->16).
// ---------------------------------------------------------------------------
__global__ __launch_bounds__(256) void dec3_k(
    const u16* __restrict__ A2, const u16* __restrict__ wg,
    const float* __restrict__ bias, float* __restrict__ out)
{
    const int tid = threadIdx.x;
    const int l = tid & 63, wvi = tid >> 6;
    const int ln = l & 15, kg = l >> 4;

    int b = blockIdx.x;
    const int mxT = b & 7;  b >>= 3;
    const int myT = b & 3;  b >>= 2;
    const int n = b;
    const int X0 = mxT * 16;
    const int MY0 = myT * 32 + wvi * 8;

    const float bv0 = bias[0], bv1 = bias[1], bv2 = bias[2];
    const short8 z8 = (short8){0, 0, 0, 0, 0, 0, 0, 0};

    for (int m8 = 0; m8 < 8; m8++) {
        const int my = MY0 + m8;
        f32x4 acc[4];
#pragma unroll
        for (int p = 0; p < 4; p++) acc[p] = (f32x4){0.f, 0.f, 0.f, 0.f};

        for (int ks = 0; ks < 4; ks++) {
            const int ci0 = ks * 32;
            short8 bfrag[3][3];
#pragma unroll
            for (int rr = 0; rr < 3; rr++) {
                const int yy = my + rr - 1;
                const bool yok = (yy >= 0) & (yy < 128);
                const int yc = min(127, max(0, yy));
#pragma unroll
                for (int sh = 0; sh < 3; sh++) {
                    const int xx = X0 + ln + sh - 1;
                    const bool ok = yok & (xx >= 0) & (xx < 128);
                    const int xc = min(127, max(0, xx));
                    const short8 v = *(const short8*)(
                        A2 + (((size_t)(n * 128 + yc) * 128 + xc) * 128 + ci0 + 8 * kg));
                    bfrag[rr][sh] = ok ? v : z8;
                }
            }
#pragma unroll
            for (int p = 0; p < 4; p++) {
                const int py = p >> 1, px = p & 1;
#pragma unroll
                for (int s = 0; s < 4; s++) {
                    const int a = s >> 1, b2 = s & 1;
                    const short8 af = *(const short8*)(
                        wg + (((size_t)(p * 4 + s) * 16 + ln) * 128 + ci0 + 8 * kg));
                    acc[p] = __builtin_amdgcn_mfma_f32_16x16x32_bf16(
                        af, bfrag[py + a][px + b2], acc[p], 0, 0, 0);
                }
            }
        }

        if (kg == 0) {
#pragma unroll
            for (int p = 0; p < 4; p++) {
                const int oy = 2 * my + (p >> 1);
                const int ox = 2 * (X0 + ln) + (p & 1);
                out[((size_t)(n * 3 + 0) * 256 + oy) * 256 + ox] = acc[p][0] + bv0;
                out[((size_t)(n * 3 + 1) * 256 + oy) * 256 + ox] = acc[p][1] + bv1;
                out[((size_t)(n * 3 + 2) * 256 + oy) * 256 + ox] = acc[p][2] + bv2;
            }
        }
    }
}

// ---------------------------------------------------------------------------
// VQ via MFMA GEMM: d2 = |c|^2 - 2 z.c ; per-lane running argmin over code
// tiles, 16-lane shfl_xor min-reduce (index tie-break = first min), then
// exact fp32 codebook-row gather. Wave = 16 vectors; block = 64.
// ---------------------------------------------------------------------------
__global__ __launch_bounds__(256) void vqm_k(
    const float* __restrict__ ze, const u16* __restrict__ cb,
    const float* __restrict__ cn, const float* __restrict__ cbk,
    float* __restrict__ zq)
{
    __shared__ float CN[512];
    __shared__ int IDX[64];
    const int tid = threadIdx.x;
    const int l = tid & 63, wvi = tid >> 6;
    const int ln = l & 15, kg = l >> 4;

    for (int i = tid; i < 512; i += 256) CN[i] = cn[i];
    __syncthreads();

    const int V0 = blockIdx.x * 64 + wvi * 16;

    short8 az[2];
#pragma unroll
    for (int ks = 0; ks < 2; ks++) {
        const float* zp = ze + (size_t)(V0 + ln) * 64 + ks * 32 + 8 * kg;
        short8 t;
#pragma unroll
        for (int j = 0; j < 8; j++) t[j] = (short)f2bf(zp[j]);
        az[ks] = t;
    }

    float bval[4] = {3.4e38f, 3.4e38f, 3.4e38f, 3.4e38f};
    int bidx[4] = {0, 0, 0, 0};
    for (int nt = 0; nt < 32; nt++) {
        const int code = nt * 16 + ln;
        const short8 b0 = *(const short8*)(cb + (size_t)code * 64 + 8 * kg);
        const short8 b1 = *(const short8*)(cb + (size_t)code * 64 + 32 + 8 * kg);
        f32x4 d = (f32x4){0.f, 0.f, 0.f, 0.f};
        d = __builtin_amdgcn_mfma_f32_16x16x32_bf16(az[0], b0, d, 0, 0, 0);
        d = __builtin_amdgcn_mfma_f32_16x16x32_bf16(az[1], b1, d, 0, 0, 0);
        const float cnv = CN[code];
#pragma unroll
        for (int r = 0; r < 4; r++) {
            const float dist = cnv - 2.f * d[r];
            if (dist < bval[r]) { bval[r] = dist; bidx[r] = code; }
        }
    }
#pragma unroll
    for (int off = 1; off < 16; off <<= 1) {
#pragma unroll
        for (int r = 0; r < 4; r++) {
            const float ov = __shfl_xor(bval[r], off);
            const int oi = __shfl_xor(bidx[r], off);
            if (ov < bval[r] || (ov == bval[r] && oi < bidx[r])) {
                bval[r] = ov; bidx[r] = oi;
            }
        }
    }
    if (ln == 0) {
#pragma unroll
        for (int r = 0; r < 4; r++) IDX[wvi * 16 + 4 * kg + r] = bidx[r];
    }
    __syncthreads();

    const int vs = tid >> 2, ch = tid & 3;
    const int bi = IDX[vs];
    const float4* sp = (const float4*)(cbk + (size_t)bi * 64 + ch * 16);
    float4* dp = (float4*)(zq + ((size_t)blockIdx.x * 64 + vs) * 64 + ch * 16);
#pragma unroll
    for (int q = 0; q < 4; q++) dp[q] = sp[q];
}

// ---------------------------------------------------------------------------
extern "C" void kernel_launch(void* const* d_in, const int* in_sizes, int n_in,
                              void* d_out, int out_size, void* d_ws, size_t ws_size,
                              hipStream_t stream)
{
    (void)in_sizes; (void)n_in; (void)out_size; (void)ws_size;

    const float* x   = (const float*)d_in[0];
    const float* ew1 = (const float*)d_in[1];
    const float* eb1 = (const float*)d_in[2];
    const float* ew2 = (const float*)d_in[3];
    const float* eb2 = (const float*)d_in[4];
    const float* ew3 = (const float*)d_in[5];
    const float* eb3 = (const float*)d_in[6];
    const float* cbk = (const float*)d_in[7];
    const float* dw1 = (const float*)d_in[8];
    const float* db1 = (const float*)d_in[9];
    const float* dw2 = (const float*)d_in[10];
    const float* db2 = (const float*)d_in[11];
    const float* dw3 = (const float*)d_in[12];
    const float* db3 = (const float*)d_in[13];

    u16* P = (u16*)d_ws;                              // 134,217,728 B
    u16* A2 = P;                                      // deconv2 out (P dead)
    u16* B = (u16*)((char*)d_ws + 134217728);         // 33,554,432 B
    u16* Wg2 = (u16*)((char*)d_ws + 167772160);       // 262144 elems
    u16* Wg3 = Wg2 + 262144;                          // 73728
    u16* Wg4 = Wg3 + 73728;                           // 73728
    u16* Wg5 = Wg4 + 73728;                           // 262144
    u16* Wg6 = Wg5 + 262144;                          // 32768 (dec3)
    u16* CB  = Wg6 + 32768;                           // 32768 (codebook bf16)
    float* CNg = (float*)(CB + 32768);                // 512 floats

    float* xr = (float*)d_out;
    float* ze = xr + (size_t)32 * 3 * 256 * 256;
    float* zq = ze + (size_t)32 * 64 * 64 * 64;

    g_enc2<<<1024, 256, 0, stream>>>(ew2, Wg2);
    g_k3<<<288, 256, 0, stream>>>(ew3, Wg3, 128, 64);
    g_k3<<<288, 256, 0, stream>>>(dw1, Wg4, 64, 128);
    g_dec2<<<1024, 256, 0, stream>>>(dw2, Wg5);
    g_dec3<<<128, 256, 0, stream>>>(dw3, Wg6);
    g_cbk<<<128, 256, 0, stream>>>(cbk, CB, CNg);

    enc1_k<<<4096, dim3(16, 16), 0, stream>>>(x, ew1, eb1, P);

    // enc2: 4 parity planes k2 -> B (relu)
    conv_mx<2, 2, 4, false, false, true, u16, u16><<<2 * 32 * 32, 256, 0, stream>>>(
        P, Wg2, eb2, B, 128, 2);
    // enc3: k3 -> ze (fp32)
    conv_mx<3, 3, 1, false, false, false, u16, float><<<1 * 32 * 32, 256, 0, stream>>>(
        B, Wg3, eb3, ze, 128, 1);
    // VQ
    vqm_k<<<2048, 256, 0, stream>>>(ze, CB, CNg, cbk, zq);
    // dec1: k3 -> B (relu)
    conv_mx<3, 3, 1, false, false, true, float, u16><<<2 * 32 * 32, 256, 0, stream>>>(
        zq, Wg4, db1, B, 64, 2);
    // deconv2: k2 x 4 parities -> A2 channel-last (relu)
    conv_mx<2, 2, 1, true, true, true, u16, u16><<<dim3(2 * 32 * 32, 4), 256, 0, stream>>>(
        B, Wg5, db2, A2, 128, 2);
    // deconv3: MFMA, parity-fused, channel-last input -> x_recon
    dec3_k<<<1024, 256, 0, stream>>>(A2, Wg6, db3, xr);
}

// Round 6
// 984.542 us; speedup vs baseline: 10.4386x; 1.7780x over previous
//
#include <hip/hip_runtime.h>
#include <hip/hip_bf16.h>

// VQ-VAE forward. R6: channel-last bf16 intermediates everywhere; conv_mx2
// with 16B staging copies, ds_read_b128 fragments (pad-40 LDS), 2 co-tiles
// per wave (B-frag reuse). fp32 in/out, fp32 accumulate.

typedef unsigned short u16;
typedef unsigned int u32;
typedef unsigned long long u64;
typedef __attribute__((ext_vector_type(8))) short short8;
typedef __attribute__((ext_vector_type(4))) float f32x4;

__device__ __forceinline__ float bf2f(u16 u) {
    union { u32 i; float f; } x; x.i = ((u32)u) << 16; return x.f;
}
__device__ __forceinline__ u16 f2bf(float f) {
    __hip_bfloat16 h = __float2bfloat16(f);
    return *reinterpret_cast<u16*>(&h);
}

// ---------------------------------------------------------------------------
// Weight gathers into MFMA layouts (bf16, ci innermost).
// ---------------------------------------------------------------------------
__global__ void g_k3(const float* __restrict__ w, u16* __restrict__ wg,
                     int CIN, int COUT)   // OIHW k3: wg[(s*COUT+co)*CIN+ci]
{
    int idx = blockIdx.x * 256 + threadIdx.x;
    if (idx >= 9 * CIN * COUT) return;
    int ci = idx % CIN;
    int co = (idx / CIN) % COUT;
    int s  = idx / (CIN * COUT);
    wg[idx] = f2bf(w[(co * CIN + ci) * 9 + s]);
}

__global__ void g_enc2(const float* __restrict__ w, u16* __restrict__ wg)
{
    int idx = blockIdx.x * 256 + threadIdx.x;   // p(4) s(4) co(128) ci(128)
    int ci = idx & 127, co = (idx >> 7) & 127, s = (idx >> 14) & 3, p = idx >> 16;
    int a = p >> 1, b = p & 1, j = s >> 1, i = s & 1;
    int ky = (1 - a) + 2 * j, kx = (1 - b) + 2 * i;
    wg[idx] = f2bf(w[((co << 7 | ci) << 4) + ky * 4 + kx]);
}

__global__ void g_dec2(const float* __restrict__ w, u16* __restrict__ wg)
{
    int idx = blockIdx.x * 256 + threadIdx.x;   // p(4) s(4) co(128) ci(128)
    int ci = idx & 127, co = (idx >> 7) & 127, s = (idx >> 14) & 3, p = idx >> 16;
    int py = p >> 1, px = p & 1, j = s >> 1, i = s & 1;
    wg[idx] = f2bf(w[((ci << 7 | co) << 4) + (3 - (py + 2 * j)) * 4 + (3 - (px + 2 * i))]);
}

__global__ void g_dec3(const float* __restrict__ w, u16* __restrict__ wg)
{
    int idx = blockIdx.x * 256 + threadIdx.x;   // 4*4*16*128 = 32768
    if (idx >= 32768) return;
    int ci = idx & 127;
    int co = (idx >> 7) & 15;
    int s  = (idx >> 11) & 3;
    int p  = idx >> 13;
    int a = s >> 1, b2 = s & 1, py = p >> 1, px = p & 1;
    float v = 0.f;
    if (co < 3) v = w[(ci * 3 + co) * 16 + (3 - (py + 2 * a)) * 4 + (3 - (px + 2 * b2))];
    wg[idx] = f2bf(v);
}

__global__ void g_cbk(const float* __restrict__ cbk, u16* __restrict__ cb,
                      float* __restrict__ cn)
{
    int idx = blockIdx.x * 256 + threadIdx.x;   // 32768
    if (idx >= 32768) return;
    cb[idx] = f2bf(cbk[idx]);
    if (idx < 512) {
        float s = 0.f;
        const float* r = cbk + idx * 64;
        for (int i = 0; i < 64; i++) s += r[i] * r[i];
        cn[idx] = s;
    }
}

// zq (fp32 NCHW) -> channel-last bf16 [n][y][x][64]
__global__ __launch_bounds__(256) void zqt_k(
    const float* __restrict__ zq, u16* __restrict__ out)
{
    __shared__ float t[64][65];
    const int tid = threadIdx.x;
    const int n = blockIdx.x >> 6, y = blockIdx.x & 63;
    for (int idx = tid; idx < 4096; idx += 256) {
        int xx = idx & 63, ci = idx >> 6;
        t[ci][xx] = zq[(((size_t)n * 64 + ci) * 64 + y) * 64 + xx];
    }
    __syncthreads();
    for (int idx = tid; idx < 4096; idx += 256) {
        int ci = idx & 63, xx = idx >> 6;
        out[(((size_t)n * 64 + y) * 64 + xx) * 64 + ci] = f2bf(t[ci][xx]);
    }
}

// ---------------------------------------------------------------------------
// enc1: k4 s2 p1, CIN=3, 256x256 -> 128x128, relu; output = 4 parity planes,
// CHANNEL-LAST: P[n][p][y][x][128]. Block (16,16), thread 2x2 quad x 16 co.
// ---------------------------------------------------------------------------
__global__ __launch_bounds__(256) void enc1_k(
    const float* __restrict__ x, const float* __restrict__ w,
    const float* __restrict__ bias, u16* __restrict__ P)
{
    __shared__ float xin[3 * 67 * 68];
    __shared__ float wl[3 * 16 * 16];

    const int tx = threadIdx.x, ty = threadIdx.y;
    const int tid = ty * 16 + tx;

    int b = blockIdx.x;
    const int cob = b & 7;  b >>= 3;
    const int TXi = b & 3;  b >>= 2;
    const int TYi = b & 3;  b >>= 2;
    const int n = b;

    for (int i = tid; i < 3 * 16 * 16; i += 256) {
        int co = i & 15, s = (i >> 4) & 15, ci = i >> 8;
        wl[i] = w[((cob * 16 + co) * 3 + ci) * 16 + s];
    }
    const int RY0 = 64 * TYi - 1, RX0 = 64 * TXi - 1;
    for (int it = 0; it < 53; it++) {
        int idx = it * 256 + tid;
        if (idx < 3 * 67 * 67) {
            int col = idx % 67;
            int row = (idx / 67) % 67;
            int ci  = idx / (67 * 67);
            int gr = RY0 + row, gc = RX0 + col;
            float v = 0.f;
            if (gr >= 0 && gr < 256 && gc >= 0 && gc < 256)
                v = x[((n * 3 + ci) * 256 + gr) * 256 + gc];
            xin[(ci * 67 + row) * 68 + col] = v;
        }
    }
    __syncthreads();

    float acc[16][4];
#pragma unroll
    for (int c = 0; c < 16; c++)
#pragma unroll
        for (int q = 0; q < 4; q++) acc[c][q] = 0.f;

#pragma unroll
    for (int ky = 0; ky < 4; ky++)
#pragma unroll
        for (int kx = 0; kx < 4; kx++)
#pragma unroll
            for (int ci = 0; ci < 3; ci++) {
                float xv[4];
#pragma unroll
                for (int qy = 0; qy < 2; qy++)
#pragma unroll
                    for (int qx = 0; qx < 2; qx++) {
                        int iyl = 2 * (2 * ty + qy) + ky;
                        int ixl = 2 * (2 * tx + qx) + kx;
                        xv[qy * 2 + qx] = xin[(ci * 67 + iyl) * 68 + ixl];
                    }
                const float* wrow = &wl[(ci * 16 + (ky * 4 + kx)) * 16];
#pragma unroll
                for (int co = 0; co < 16; co++) {
                    float wv = wrow[co];
#pragma unroll
                    for (int q = 0; q < 4; q++) acc[co][q] += xv[q] * wv;
                }
            }

#pragma unroll
    for (int p = 0; p < 4; p++) {
        short8 s0, s1;
#pragma unroll
        for (int co = 0; co < 8; co++)
            s0[co] = (short)f2bf(fmaxf(acc[co][p] + bias[cob * 16 + co], 0.f));
#pragma unroll
        for (int co = 0; co < 8; co++)
            s1[co] = (short)f2bf(fmaxf(acc[8 + co][p] + bias[cob * 16 + 8 + co], 0.f));
        size_t addr = ((((size_t)(n * 4 + p) * 64 + (TYi * 16 + ty)) * 64
                        + (TXi * 16 + tx)) * 128) + cob * 16;
        *(short8*)(P + addr) = s0;
        *(short8*)(P + addr + 8) = s1;
    }
}

// ---------------------------------------------------------------------------
// conv_mx2: stride-1 MFMA conv on 64x64 channel-last planes.
// J x I taps, NP planes, SY spatial wave-split, OUTM: 0 = bf16 CL [64][64][COUT]
// (relu), 1 = fp32 NCHW (no relu), 2 = deconv parity CL [128][128][128] (relu).
// Block 256 = 4 waves = (4/SY co-waves) x (SY row-groups); 2 co-tiles/wave.
// LDS: [2*SY+2 rows][68 cols][ci 32 pad 40] bf16; fragment = ds_read_b128.
// ---------------------------------------------------------------------------
template<int J, int I, int NP, int SY, int OUTM>
__global__ __launch_bounds__(256) void conv_mx2(
    const u16* __restrict__ x, const u16* __restrict__ wg,
    const float* __restrict__ bias, void* __restrict__ yv,
    int CIN, int COUT)
{
    constexpr int RS = 2 * SY + 2;
    __shared__ u16 XL[RS * 68 * 40];
    constexpr int NCW = 4 / SY;

    const int tid = threadIdx.x;
    const int l = tid & 63, wv = tid >> 6;
    const int kg = l >> 4, ln = l & 15;
    const int cw = wv % NCW, g = wv / NCW;

    int b = blockIdx.x;
    constexpr int TILES = 64 / (2 * SY);
    const int tile = b % TILES;  b /= TILES;
    const int n = b;
    const int OY0 = tile * (2 * SY);
    const int pc = (OUTM == 2) ? blockIdx.y : 0;

    f32x4 acc[2][8];
#pragma unroll
    for (int u = 0; u < 2; u++)
#pragma unroll
        for (int t = 0; t < 8; t++) acc[u][t] = (f32x4){0.f, 0.f, 0.f, 0.f};

    const u16* xn = x + (size_t)n * NP * CIN * 4096;
    const int co0 = cw * 32 + ln;

    for (int p = 0; p < NP; p++) {
        int dy0, dx0;
        const u16* wgp;
        if (OUTM == 2) {
            dy0 = (pc >> 1) - 1; dx0 = (pc & 1) - 1;
            wgp = wg + (size_t)pc * J * I * COUT * CIN;
        } else if (NP == 4) {
            dy0 = -(p >> 1); dx0 = -(p & 1);
            wgp = wg + (size_t)p * J * I * COUT * CIN;
        } else {
            dy0 = -1; dx0 = -1; wgp = wg;
        }
        const u16* xp = xn + (size_t)p * CIN * 4096;

        for (int ci0 = 0; ci0 < CIN; ci0 += 32) {
            __syncthreads();
            constexpr int TASKS = RS * 68 * 4;
            for (int idx = tid; idx < TASKS; idx += 256) {
                const int q  = idx & 3;
                const int cc = (idx >> 2) % 68;
                const int r  = (idx >> 2) / 68;
                const int gr = OY0 - 1 + r;
                const int gx = cc - 1;
                short8 v = (short8){0, 0, 0, 0, 0, 0, 0, 0};
                if (gr >= 0 && gr < 64 && gx >= 0 && gx < 64)
                    v = *(const short8*)(xp + (size_t)(gr * 64 + gx) * CIN
                                         + ci0 + 8 * q);
                *(short8*)(XL + (r * 68 + cc) * 40 + 8 * q) = v;
            }
            __syncthreads();

#define TAP_ROW(jv)                                                          \
            {                                                                \
                short8 wf0[I], wf1[I];                                       \
                _Pragma("unroll")                                            \
                for (int i = 0; i < I; i++) {                                \
                    const size_t wb = ((size_t)((jv) * I + i) * COUT + co0)  \
                                      * CIN + ci0 + 8 * kg;                  \
                    wf0[i] = *(const short8*)(wgp + wb);                     \
                    wf1[i] = *(const short8*)(wgp + wb + (size_t)16 * CIN);  \
                }                                                            \
                _Pragma("unroll")                                            \
                for (int i = 0; i < I; i++) {                                \
                    _Pragma("unroll")                                        \
                    for (int t = 0; t < 8; t++) {                            \
                        const int rf = (t >> 2) + 2 * g + dy0 + 1 + (jv);    \
                        const int cf = (t & 3) * 16 + ln + dx0 + 1 + i;      \
                        const short8 bf = *(const short8*)(                  \
                            XL + (rf * 68 + cf) * 40 + 8 * kg);              \
                        acc[0][t] = __builtin_amdgcn_mfma_f32_16x16x32_bf16( \
                            wf0[i], bf, acc[0][t], 0, 0, 0);                 \
                        acc[1][t] = __builtin_amdgcn_mfma_f32_16x16x32_bf16( \
                            wf1[i], bf, acc[1][t], 0, 0, 0);                 \
                    }                                                        \
                }                                                            \
            }

            if constexpr (J == 2) {
                TAP_ROW(0); TAP_ROW(1);
            } else {
#pragma unroll 1
                for (int j = 0; j < J; j++) TAP_ROW(j);
            }
#undef TAP_ROW
        }
    }

    // epilogue: D row (4kg+rr) = co offset, D col (ln) = pixel
#pragma unroll
    for (int u = 0; u < 2; u++) {
        const int cob = cw * 32 + u * 16 + 4 * kg;
#pragma unroll
        for (int t = 0; t < 8; t++) {
            const int oy = OY0 + 2 * g + (t >> 2);
            const int ox = (t & 3) * 16 + ln;
            if constexpr (OUTM == 1) {
                float* out = (float*)yv;
#pragma unroll
                for (int rr = 0; rr < 4; rr++)
                    out[(((size_t)n * COUT + cob + rr) * 64 + oy) * 64 + ox]
                        = acc[u][t][rr] + bias[cob + rr];
            } else {
                u16 pk[4];
#pragma unroll
                for (int rr = 0; rr < 4; rr++)
                    pk[rr] = f2bf(fmaxf(acc[u][t][rr] + bias[cob + rr], 0.f));
                if constexpr (OUTM == 0) {
                    *(u64*)((u16*)yv + ((size_t)(n * 64 + oy) * 64 + ox) * COUT
                            + cob) = *(const u64*)pk;
                } else {
                    const int OY = 2 * oy + (pc >> 1), OX = 2 * ox + (pc & 1);
                    *(u64*)((u16*)yv + ((size_t)(n * 128 + OY) * 128 + OX) * 128
                            + cob) = *(const u64*)pk;
                }
            }
        }
    }
}

// ---------------------------------------------------------------------------
// deconv3 via MFMA: A2[n][y][x][128] bf16 channel-last, 4 parities fused.
// ---------------------------------------------------------------------------
__global__ __launch_bounds__(256) void dec3_k(
    const u16* __restrict__ A2, const u16* __restrict__ wg,
    const float* __restrict__ bias, float* __restrict__ out)
{
    const int tid = threadIdx.x;
    const int l = tid & 63, wvi = tid >> 6;
    const int ln = l & 15, kg = l >> 4;

    int b = blockIdx.x;
    const int mxT = b & 7;  b >>= 3;
    const int myT = b & 3;  b >>= 2;
    const int n = b;
    const int X0 = mxT * 16;
    const int MY0 = myT * 32 + wvi * 8;

    const float bv0 = bias[0], bv1 = bias[1], bv2 = bias[2];
    const short8 z8 = (short8){0, 0, 0, 0, 0, 0, 0, 0};

    for (int m8 = 0; m8 < 8; m8++) {
        const int my = MY0 + m8;
        f32x4 acc[4];
#pragma unroll
        for (int p = 0; p < 4; p++) acc[p] = (f32x4){0.f, 0.f, 0.f, 0.f};

        for (int ks = 0; ks < 4; ks++) {
            const int ci0 = ks * 32;
            short8 bfrag[3][3];
#pragma unroll
            for (int rr = 0; rr < 3; rr++) {
                const int yy = my + rr - 1;
                const bool yok = (yy >= 0) & (yy < 128);
                const int yc = min(127, max(0, yy));
#pragma unroll
                for (int sh = 0; sh < 3; sh++) {
                    const int xx = X0 + ln + sh - 1;
                    const bool ok = yok & (xx >= 0) & (xx < 128);
                    const int xc = min(127, max(0, xx));
                    const short8 v = *(const short8*)(
                        A2 + (((size_t)(n * 128 + yc) * 128 + xc) * 128 + ci0 + 8 * kg));
                    bfrag[rr][sh] = ok ? v : z8;
                }
            }
#pragma unroll
            for (int p = 0; p < 4; p++) {
                const int py = p >> 1, px = p & 1;
#pragma unroll
                for (int s = 0; s < 4; s++) {
                    const int a = s >> 1, b2 = s & 1;
                    const short8 af = *(const short8*)(
                        wg + (((size_t)(p * 4 + s) * 16 + ln) * 128 + ci0 + 8 * kg));
                    acc[p] = __builtin_amdgcn_mfma_f32_16x16x32_bf16(
                        af, bfrag[py + a][px + b2], acc[p], 0, 0, 0);
                }
            }
        }

        if (kg == 0) {
#pragma unroll
            for (int p = 0; p < 4; p++) {
                const int oy = 2 * my + (p >> 1);
                const int ox = 2 * (X0 + ln) + (p & 1);
                out[((size_t)(n * 3 + 0) * 256 + oy) * 256 + ox] = acc[p][0] + bv0;
                out[((size_t)(n * 3 + 1) * 256 + oy) * 256 + ox] = acc[p][1] + bv1;
                out[((size_t)(n * 3 + 2) * 256 + oy) * 256 + ox] = acc[p][2] + bv2;
            }
        }
    }
}

// ---------------------------------------------------------------------------
// VQ via MFMA GEMM (validated R5).
// ---------------------------------------------------------------------------
__global__ __launch_bounds__(256) void vqm_k(
    const float* __restrict__ ze, const u16* __restrict__ cb,
    const float* __restrict__ cn, const float* __restrict__ cbk,
    float* __restrict__ zq)
{
    __shared__ float CN[512];
    __shared__ int IDX[64];
    const int tid = threadIdx.x;
    const int l = tid & 63, wvi = tid >> 6;
    const int ln = l & 15, kg = l >> 4;

    for (int i = tid; i < 512; i += 256) CN[i] = cn[i];
    __syncthreads();

    const int V0 = blockIdx.x * 64 + wvi * 16;

    short8 az[2];
#pragma unroll
    for (int ks = 0; ks < 2; ks++) {
        const float* zp = ze + (size_t)(V0 + ln) * 64 + ks * 32 + 8 * kg;
        short8 t;
#pragma unroll
        for (int j = 0; j < 8; j++) t[j] = (short)f2bf(zp[j]);
        az[ks] = t;
    }

    float bval[4] = {3.4e38f, 3.4e38f, 3.4e38f, 3.4e38f};
    int bidx[4] = {0, 0, 0, 0};
    for (int nt = 0; nt < 32; nt++) {
        const int code = nt * 16 + ln;
        const short8 b0 = *(const short8*)(cb + (size_t)code * 64 + 8 * kg);
        const short8 b1 = *(const short8*)(cb + (size_t)code * 64 + 32 + 8 * kg);
        f32x4 d = (f32x4){0.f, 0.f, 0.f, 0.f};
        d = __builtin_amdgcn_mfma_f32_16x16x32_bf16(az[0], b0, d, 0, 0, 0);
        d = __builtin_amdgcn_mfma_f32_16x16x32_bf16(az[1], b1, d, 0, 0, 0);
        const float cnv = CN[code];
#pragma unroll
        for (int r = 0; r < 4; r++) {
            const float dist = cnv - 2.f * d[r];
            if (dist < bval[r]) { bval[r] = dist; bidx[r] = code; }
        }
    }
#pragma unroll
    for (int off = 1; off < 16; off <<= 1) {
#pragma unroll
        for (int r = 0; r < 4; r++) {
            const float ov = __shfl_xor(bval[r], off);
            const int oi = __shfl_xor(bidx[r], off);
            if (ov < bval[r] || (ov == bval[r] && oi < bidx[r])) {
                bval[r] = ov; bidx[r] = oi;
            }
        }
    }
    if (ln == 0) {
#pragma unroll
        for (int r = 0; r < 4; r++) IDX[wvi * 16 + 4 * kg + r] = bidx[r];
    }
    __syncthreads();

    const int vs = tid >> 2, ch = tid & 3;
    const int bi = IDX[vs];
    const float4* sp = (const float4*)(cbk + (size_t)bi * 64 + ch * 16);
    float4* dp = (float4*)(zq + ((size_t)blockIdx.x * 64 + vs) * 64 + ch * 16);
#pragma unroll
    for (int q = 0; q < 4; q++) dp[q] = sp[q];
}

// ---------------------------------------------------------------------------
extern "C" void kernel_launch(void* const* d_in, const int* in_sizes, int n_in,
                              void* d_out, int out_size, void* d_ws, size_t ws_size,
                              hipStream_t stream)
{
    (void)in_sizes; (void)n_in; (void)out_size; (void)ws_size;

    const float* x   = (const float*)d_in[0];
    const float* ew1 = (const float*)d_in[1];
    const float* eb1 = (const float*)d_in[2];
    const float* ew2 = (const float*)d_in[3];
    const float* eb2 = (const float*)d_in[4];
    const float* ew3 = (const float*)d_in[5];
    const float* eb3 = (const float*)d_in[6];
    const float* cbk = (const float*)d_in[7];
    const float* dw1 = (const float*)d_in[8];
    const float* db1 = (const float*)d_in[9];
    const float* dw2 = (const float*)d_in[10];
    const float* db2 = (const float*)d_in[11];
    const float* dw3 = (const float*)d_in[12];
    const float* db3 = (const float*)d_in[13];

    // region0 (134.2 MB): P (enc1 out) -> zq_cl -> A2 (time-multiplexed)
    u16* P    = (u16*)d_ws;
    u16* ZQCL = P;
    u16* A2   = P;
    u16* B = (u16*)((char*)d_ws + 134217728);         // 33.5 MB
    u16* Wg2 = (u16*)((char*)d_ws + 167772160);       // 262144
    u16* Wg3 = Wg2 + 262144;                          // 73728
    u16* Wg4 = Wg3 + 73728;                           // 73728
    u16* Wg5 = Wg4 + 73728;                           // 262144
    u16* Wg6 = Wg5 + 262144;                          // 32768
    u16* CB  = Wg6 + 32768;                           // 32768
    float* CNg = (float*)(CB + 32768);                // 512

    float* xr = (float*)d_out;
    float* ze = xr + (size_t)32 * 3 * 256 * 256;
    float* zq = ze + (size_t)32 * 64 * 64 * 64;

    g_enc2<<<1024, 256, 0, stream>>>(ew2, Wg2);
    g_k3<<<288, 256, 0, stream>>>(ew3, Wg3, 128, 64);
    g_k3<<<288, 256, 0, stream>>>(dw1, Wg4, 64, 128);
    g_dec2<<<1024, 256, 0, stream>>>(dw2, Wg5);
    g_dec3<<<128, 256, 0, stream>>>(dw3, Wg6);
    g_cbk<<<128, 256, 0, stream>>>(cbk, CB, CNg);

    // enc1 -> P (channel-last parity planes)
    enc1_k<<<4096, dim3(16, 16), 0, stream>>>(x, ew1, eb1, P);
    // enc2: 4 planes k2 -> B (CL, relu)
    conv_mx2<2, 2, 4, 1, 0><<<32 * 32, 256, 0, stream>>>(P, Wg2, eb2, B, 128, 128);
    // enc3: k3 -> ze (fp32 NCHW)
    conv_mx2<3, 3, 1, 2, 1><<<16 * 32, 256, 0, stream>>>(B, Wg3, eb3, ze, 128, 64);
    // VQ
    vqm_k<<<2048, 256, 0, stream>>>(ze, CB, CNg, cbk, zq);
    // zq -> channel-last bf16
    zqt_k<<<2048, 256, 0, stream>>>(zq, ZQCL);
    // dec1: k3 -> B (CL, relu)
    conv_mx2<3, 3, 1, 1, 0><<<32 * 32, 256, 0, stream>>>(ZQCL, Wg4, db1, B, 64, 128);
    // deconv2: k2 x 4 parities -> A2 (CL, relu)
    conv_mx2<2, 2, 1, 1, 2><<<dim3(32 * 32, 4), 256, 0, stream>>>(B, Wg5, db2, A2, 128, 128);
    // deconv3 -> x_recon
    dec3_k<<<1024, 256, 0, stream>>>(A2, Wg6, db3, xr);
}

// Round 7
// 731.796 us; speedup vs baseline: 14.0438x; 1.3454x over previous
//
#include <hip/hip_runtime.h>
#include <hip/hip_bf16.h>

// VQ-VAE forward. R7: enc1 -> MFMA (channel-last K=64 packing, padded input,
// LDS-free B-frags). Everything else from R6 (channel-last conv_mx2 pipeline).

typedef unsigned short u16;
typedef unsigned int u32;
typedef unsigned long long u64;
typedef __attribute__((ext_vector_type(8))) short short8;
typedef __attribute__((ext_vector_type(4))) float f32x4;

__device__ __forceinline__ float bf2f(u16 u) {
    union { u32 i; float f; } x; x.i = ((u32)u) << 16; return x.f;
}
__device__ __forceinline__ u16 f2bf(float f) {
    __hip_bfloat16 h = __float2bfloat16(f);
    return *reinterpret_cast<u16*>(&h);
}

// ---------------------------------------------------------------------------
// Weight gathers (bf16, MFMA layouts).
// ---------------------------------------------------------------------------
__global__ void g_k3(const float* __restrict__ w, u16* __restrict__ wg,
                     int CIN, int COUT)   // OIHW k3: wg[(s*COUT+co)*CIN+ci]
{
    int idx = blockIdx.x * 256 + threadIdx.x;
    if (idx >= 9 * CIN * COUT) return;
    int ci = idx % CIN;
    int co = (idx / CIN) % COUT;
    int s  = idx / (CIN * COUT);
    wg[idx] = f2bf(w[(co * CIN + ci) * 9 + s]);
}

__global__ void g_enc2(const float* __restrict__ w, u16* __restrict__ wg)
{
    int idx = blockIdx.x * 256 + threadIdx.x;   // p(4) s(4) co(128) ci(128)
    int ci = idx & 127, co = (idx >> 7) & 127, s = (idx >> 14) & 3, p = idx >> 16;
    int a = p >> 1, b = p & 1, j = s >> 1, i = s & 1;
    int ky = (1 - a) + 2 * j, kx = (1 - b) + 2 * i;
    wg[idx] = f2bf(w[((co << 7 | ci) << 4) + ky * 4 + kx]);
}

__global__ void g_dec2(const float* __restrict__ w, u16* __restrict__ wg)
{
    int idx = blockIdx.x * 256 + threadIdx.x;   // p(4) s(4) co(128) ci(128)
    int ci = idx & 127, co = (idx >> 7) & 127, s = (idx >> 14) & 3, p = idx >> 16;
    int py = p >> 1, px = p & 1, j = s >> 1, i = s & 1;
    wg[idx] = f2bf(w[((ci << 7 | co) << 4) + (3 - (py + 2 * j)) * 4 + (3 - (px + 2 * i))]);
}

__global__ void g_dec3(const float* __restrict__ w, u16* __restrict__ wg)
{
    int idx = blockIdx.x * 256 + threadIdx.x;   // 4*4*16*128 = 32768
    if (idx >= 32768) return;
    int ci = idx & 127;
    int co = (idx >> 7) & 15;
    int s  = (idx >> 11) & 3;
    int p  = idx >> 13;
    int a = s >> 1, b2 = s & 1, py = p >> 1, px = p & 1;
    float v = 0.f;
    if (co < 3) v = w[(ci * 3 + co) * 16 + (3 - (py + 2 * a)) * 4 + (3 - (px + 2 * b2))];
    wg[idx] = f2bf(v);
}

// enc1 weights: wg[co*64 + ky*16 + kx*4 + ci] (ci 3->4 zero pad), OIHW k4.
__global__ void g_enc1(const float* __restrict__ w, u16* __restrict__ wg)
{
    int idx = blockIdx.x * 256 + threadIdx.x;   // 128*64 = 8192
    if (idx >= 8192) return;
    int ci = idx & 3, kx = (idx >> 2) & 3, ky = (idx >> 4) & 3, co = idx >> 6;
    float v = 0.f;
    if (ci < 3) v = w[((co * 3 + ci) * 4 + ky) * 4 + kx];
    wg[idx] = f2bf(v);
}

__global__ void g_cbk(const float* __restrict__ cbk, u16* __restrict__ cb,
                      float* __restrict__ cn)
{
    int idx = blockIdx.x * 256 + threadIdx.x;   // 32768
    if (idx >= 32768) return;
    cb[idx] = f2bf(cbk[idx]);
    if (idx < 512) {
        float s = 0.f;
        const float* r = cbk + idx * 64;
        for (int i = 0; i < 64; i++) s += r[i] * r[i];
        cn[idx] = s;
    }
}

// x (fp32 NCHW) -> x_cl[n][258][258][4] bf16, zero-padded halo + 4th channel.
__global__ __launch_bounds__(256) void xcl_k(
    const float* __restrict__ x, u16* __restrict__ xcl)
{
    const int y = blockIdx.x % 258, n = blockIdx.x / 258;
    const int gy = y - 1;
    for (int xx = threadIdx.x; xx < 258; xx += 256) {
        const int gx = xx - 1;
        u16 pk[4] = {0, 0, 0, 0};
        if (gy >= 0 && gy < 256 && gx >= 0 && gx < 256) {
            const size_t base = ((size_t)n * 3 * 256 + gy) * 256 + gx;
            pk[0] = f2bf(x[base]);
            pk[1] = f2bf(x[base + 65536]);
            pk[2] = f2bf(x[base + 131072]);
        }
        *(u64*)(xcl + ((size_t)(n * 258 + y) * 258 + xx) * 4) = *(const u64*)pk;
    }
}

// ---------------------------------------------------------------------------
// enc1 via MFMA: K=64 (4ky x 16), B-frag = one aligned 16B global load from
// x_cl; A-frags (all 128 co) in VGPRs. Output = channel-last parity planes
// P[n][p][yy][xx][128], relu. Block = 4 waves; wave = one x-parity half-row.
// ---------------------------------------------------------------------------
__global__ __launch_bounds__(256) void enc1m_k(
    const u16* __restrict__ xcl, const u16* __restrict__ wg,
    const float* __restrict__ bias, u16* __restrict__ P)
{
    const int tid = threadIdx.x;
    const int l = tid & 63, w = tid >> 6;
    const int ln = l & 15, kg = l >> 4;
    const int px = w >> 1, half = w & 1;

    const int oy = blockIdx.x & 127;
    const int n  = blockIdx.x >> 7;
    const int p  = (oy & 1) * 2 + px;
    const int yy = oy >> 1;

    // A fragments: af[u][s], co = u*16+ln, k = s*32 + 8*kg + j
    short8 af[8][2];
#pragma unroll
    for (int u = 0; u < 8; u++)
#pragma unroll
        for (int s = 0; s < 2; s++)
            af[u][s] = *(const short8*)(wg + ((u * 16 + ln) << 6) + s * 32 + 8 * kg);

    float bl[8];
#pragma unroll
    for (int u = 0; u < 8; u++) bl[u] = bias[u * 16 + 4 * kg + (ln & 3)];
    // note: bias indexed per D-row below instead (simpler): reload directly.

    const u16* xn = xcl + (size_t)n * 258 * 258 * 4;
    const int r0 = 2 * oy;                        // padded input row for ky=0

#pragma unroll
    for (int t = 0; t < 2; t++) {
        const int xq = half * 32 + t * 16 + ln;   // xx within plane (0..63)
        const int ox = px + 2 * xq;

        short8 bf[2];
#pragma unroll
        for (int s = 0; s < 2; s++) {
            const int row = r0 + 2 * s + (kg >> 1);
            bf[s] = *(const short8*)(xn + ((size_t)row * 258 + 2 * ox) * 4
                                     + (kg & 1) * 8);
        }

        f32x4 acc[8];
#pragma unroll
        for (int u = 0; u < 8; u++) acc[u] = (f32x4){0.f, 0.f, 0.f, 0.f};
#pragma unroll
        for (int u = 0; u < 8; u++) {
            acc[u] = __builtin_amdgcn_mfma_f32_16x16x32_bf16(af[u][0], bf[0], acc[u], 0, 0, 0);
            acc[u] = __builtin_amdgcn_mfma_f32_16x16x32_bf16(af[u][1], bf[1], acc[u], 0, 0, 0);
        }

#pragma unroll
        for (int u = 0; u < 8; u++) {
            const int cobase = u * 16 + 4 * kg;
            u16 pk[4];
#pragma unroll
            for (int r = 0; r < 4; r++)
                pk[r] = f2bf(fmaxf(acc[u][r] + bias[cobase + r], 0.f));
            *(u64*)(P + ((((size_t)(n * 4 + p) * 64 + yy) * 64 + xq) << 7) + cobase)
                = *(const u64*)pk;
        }
    }
}

// ---------------------------------------------------------------------------
// conv_mx2 (R6, validated): stride-1 MFMA conv on 64x64 channel-last planes.
// ---------------------------------------------------------------------------
template<int J, int I, int NP, int SY, int OUTM>
__global__ __launch_bounds__(256) void conv_mx2(
    const u16* __restrict__ x, const u16* __restrict__ wg,
    const float* __restrict__ bias, void* __restrict__ yv,
    int CIN, int COUT)
{
    constexpr int RS = 2 * SY + 2;
    __shared__ u16 XL[RS * 68 * 40];
    constexpr int NCW = 4 / SY;

    const int tid = threadIdx.x;
    const int l = tid & 63, wv = tid >> 6;
    const int kg = l >> 4, ln = l & 15;
    const int cw = wv % NCW, g = wv / NCW;

    int b = blockIdx.x;
    constexpr int TILES = 64 / (2 * SY);
    const int tile = b % TILES;  b /= TILES;
    const int n = b;
    const int OY0 = tile * (2 * SY);
    const int pc = (OUTM == 2) ? blockIdx.y : 0;

    f32x4 acc[2][8];
#pragma unroll
    for (int u = 0; u < 2; u++)
#pragma unroll
        for (int t = 0; t < 8; t++) acc[u][t] = (f32x4){0.f, 0.f, 0.f, 0.f};

    const u16* xn = x + (size_t)n * NP * CIN * 4096;
    const int co0 = cw * 32 + ln;

    for (int p = 0; p < NP; p++) {
        int dy0, dx0;
        const u16* wgp;
        if (OUTM == 2) {
            dy0 = (pc >> 1) - 1; dx0 = (pc & 1) - 1;
            wgp = wg + (size_t)pc * J * I * COUT * CIN;
        } else if (NP == 4) {
            dy0 = -(p >> 1); dx0 = -(p & 1);
            wgp = wg + (size_t)p * J * I * COUT * CIN;
        } else {
            dy0 = -1; dx0 = -1; wgp = wg;
        }
        const u16* xp = xn + (size_t)p * CIN * 4096;

        for (int ci0 = 0; ci0 < CIN; ci0 += 32) {
            __syncthreads();
            constexpr int TASKS = RS * 68 * 4;
            for (int idx = tid; idx < TASKS; idx += 256) {
                const int q  = idx & 3;
                const int cc = (idx >> 2) % 68;
                const int r  = (idx >> 2) / 68;
                const int gr = OY0 - 1 + r;
                const int gx = cc - 1;
                short8 v = (short8){0, 0, 0, 0, 0, 0, 0, 0};
                if (gr >= 0 && gr < 64 && gx >= 0 && gx < 64)
                    v = *(const short8*)(xp + (size_t)(gr * 64 + gx) * CIN
                                         + ci0 + 8 * q);
                *(short8*)(XL + (r * 68 + cc) * 40 + 8 * q) = v;
            }
            __syncthreads();

#define TAP_ROW(jv)                                                          \
            {                                                                \
                short8 wf0[I], wf1[I];                                       \
                _Pragma("unroll")                                            \
                for (int i = 0; i < I; i++) {                                \
                    const size_t wb = ((size_t)((jv) * I + i) * COUT + co0)  \
                                      * CIN + ci0 + 8 * kg;                  \
                    wf0[i] = *(const short8*)(wgp + wb);                     \
                    wf1[i] = *(const short8*)(wgp + wb + (size_t)16 * CIN);  \
                }                                                            \
                _Pragma("unroll")                                            \
                for (int i = 0; i < I; i++) {                                \
                    _Pragma("unroll")                                        \
                    for (int t = 0; t < 8; t++) {                            \
                        const int rf = (t >> 2) + 2 * g + dy0 + 1 + (jv);    \
                        const int cf = (t & 3) * 16 + ln + dx0 + 1 + i;      \
                        const short8 bf = *(const short8*)(                  \
                            XL + (rf * 68 + cf) * 40 + 8 * kg);              \
                        acc[0][t] = __builtin_amdgcn_mfma_f32_16x16x32_bf16( \
                            wf0[i], bf, acc[0][t], 0, 0, 0);                 \
                        acc[1][t] = __builtin_amdgcn_mfma_f32_16x16x32_bf16( \
                            wf1[i], bf, acc[1][t], 0, 0, 0);                 \
                    }                                                        \
                }                                                            \
            }

            if constexpr (J == 2) {
                TAP_ROW(0); TAP_ROW(1);
            } else {
#pragma unroll 1
                for (int j = 0; j < J; j++) TAP_ROW(j);
            }
#undef TAP_ROW
        }
    }

#pragma unroll
    for (int u = 0; u < 2; u++) {
        const int cob = cw * 32 + u * 16 + 4 * kg;
#pragma unroll
        for (int t = 0; t < 8; t++) {
            const int oy = OY0 + 2 * g + (t >> 2);
            const int ox = (t & 3) * 16 + ln;
            if constexpr (OUTM == 1) {
                float* out = (float*)yv;
#pragma unroll
                for (int rr = 0; rr < 4; rr++)
                    out[(((size_t)n * COUT + cob + rr) * 64 + oy) * 64 + ox]
                        = acc[u][t][rr] + bias[cob + rr];
            } else {
                u16 pk[4];
#pragma unroll
                for (int rr = 0; rr < 4; rr++)
                    pk[rr] = f2bf(fmaxf(acc[u][t][rr] + bias[cob + rr], 0.f));
                if constexpr (OUTM == 0) {
                    *(u64*)((u16*)yv + ((size_t)(n * 64 + oy) * 64 + ox) * COUT
                            + cob) = *(const u64*)pk;
                } else {
                    const int OY = 2 * oy + (pc >> 1), OX = 2 * ox + (pc & 1);
                    *(u64*)((u16*)yv + ((size_t)(n * 128 + OY) * 128 + OX) * 128
                            + cob) = *(const u64*)pk;
                }
            }
        }
    }
}

// ---------------------------------------------------------------------------
// deconv3 via MFMA (R5/R6, validated).
// ---------------------------------------------------------------------------
__global__ __launch_bounds__(256) void dec3_k(
    const u16* __restrict__ A2, const u16* __restrict__ wg,
    const float* __restrict__ bias, float* __restrict__ out)
{
    const int tid = threadIdx.x;
    const int l = tid & 63, wvi = tid >> 6;
    const int ln = l & 15, kg = l >> 4;

    int b = blockIdx.x;
    const int mxT = b & 7;  b >>= 3;
    const int myT = b & 3;  b >>= 2;
    const int n = b;
    const int X0 = mxT * 16;
    const int MY0 = myT * 32 + wvi * 8;

    const float bv0 = bias[0], bv1 = bias[1], bv2 = bias[2];
    const short8 z8 = (short8){0, 0, 0, 0, 0, 0, 0, 0};

    for (int m8 = 0; m8 < 8; m8++) {
        const int my = MY0 + m8;
        f32x4 acc[4];
#pragma unroll
        for (int p = 0; p < 4; p++) acc[p] = (f32x4){0.f, 0.f, 0.f, 0.f};

        for (int ks = 0; ks < 4; ks++) {
            const int ci0 = ks * 32;
            short8 bfrag[3][3];
#pragma unroll
            for (int rr = 0; rr < 3; rr++) {
                const int yy = my + rr - 1;
                const bool yok = (yy >= 0) & (yy < 128);
                const int yc = min(127, max(0, yy));
#pragma unroll
                for (int sh = 0; sh < 3; sh++) {
                    const int xx = X0 + ln + sh - 1;
                    const bool ok = yok & (xx >= 0) & (xx < 128);
                    const int xc = min(127, max(0, xx));
                    const short8 v = *(const short8*)(
                        A2 + (((size_t)(n * 128 + yc) * 128 + xc) * 128 + ci0 + 8 * kg));
                    bfrag[rr][sh] = ok ? v : z8;
                }
            }
#pragma unroll
            for (int p = 0; p < 4; p++) {
                const int py = p >> 1, px = p & 1;
#pragma unroll
                for (int s = 0; s < 4; s++) {
                    const int a = s >> 1, b2 = s & 1;
                    const short8 afr = *(const short8*)(
                        wg + (((size_t)(p * 4 + s) * 16 + ln) * 128 + ci0 + 8 * kg));
                    acc[p] = __builtin_amdgcn_mfma_f32_16x16x32_bf16(
                        afr, bfrag[py + a][px + b2], acc[p], 0, 0, 0);
                }
            }
        }

        if (kg == 0) {
#pragma unroll
            for (int p = 0; p < 4; p++) {
                const int oy = 2 * my + (p >> 1);
                const int ox = 2 * (X0 + ln) + (p & 1);
                out[((size_t)(n * 3 + 0) * 256 + oy) * 256 + ox] = acc[p][0] + bv0;
                out[((size_t)(n * 3 + 1) * 256 + oy) * 256 + ox] = acc[p][1] + bv1;
                out[((size_t)(n * 3 + 2) * 256 + oy) * 256 + ox] = acc[p][2] + bv2;
            }
        }
    }
}

// ---------------------------------------------------------------------------
// VQ via MFMA GEMM (R5, validated).
// ---------------------------------------------------------------------------
__global__ __launch_bounds__(256) void vqm_k(
    const float* __restrict__ ze, const u16* __restrict__ cb,
    const float* __restrict__ cn, const float* __restrict__ cbk,
    float* __restrict__ zq)
{
    __shared__ float CN[512];
    __shared__ int IDX[64];
    const int tid = threadIdx.x;
    const int l = tid & 63, wvi = tid >> 6;
    const int ln = l & 15, kg = l >> 4;

    for (int i = tid; i < 512; i += 256) CN[i] = cn[i];
    __syncthreads();

    const int V0 = blockIdx.x * 64 + wvi * 16;

    short8 az[2];
#pragma unroll
    for (int ks = 0; ks < 2; ks++) {
        const float* zp = ze + (size_t)(V0 + ln) * 64 + ks * 32 + 8 * kg;
        short8 t;
#pragma unroll
        for (int j = 0; j < 8; j++) t[j] = (short)f2bf(zp[j]);
        az[ks] = t;
    }

    float bval[4] = {3.4e38f, 3.4e38f, 3.4e38f, 3.4e38f};
    int bidx[4] = {0, 0, 0, 0};
    for (int nt = 0; nt < 32; nt++) {
        const int code = nt * 16 + ln;
        const short8 b0 = *(const short8*)(cb + (size_t)code * 64 + 8 * kg);
        const short8 b1 = *(const short8*)(cb + (size_t)code * 64 + 32 + 8 * kg);
        f32x4 d = (f32x4){0.f, 0.f, 0.f, 0.f};
        d = __builtin_amdgcn_mfma_f32_16x16x32_bf16(az[0], b0, d, 0, 0, 0);
        d = __builtin_amdgcn_mfma_f32_16x16x32_bf16(az[1], b1, d, 0, 0, 0);
        const float cnv = CN[code];
#pragma unroll
        for (int r = 0; r < 4; r++) {
            const float dist = cnv - 2.f * d[r];
            if (dist < bval[r]) { bval[r] = dist; bidx[r] = code; }
        }
    }
#pragma unroll
    for (int off = 1; off < 16; off <<= 1) {
#pragma unroll
        for (int r = 0; r < 4; r++) {
            const float ov = __shfl_xor(bval[r], off);
            const int oi = __shfl_xor(bidx[r], off);
            if (ov < bval[r] || (ov == bval[r] && oi < bidx[r])) {
                bval[r] = ov; bidx[r] = oi;
            }
        }
    }
    if (ln == 0) {
#pragma unroll
        for (int r = 0; r < 4; r++) IDX[wvi * 16 + 4 * kg + r] = bidx[r];
    }
    __syncthreads();

    const int vs = tid >> 2, ch = tid & 3;
    const int bi = IDX[vs];
    const float4* sp = (const float4*)(cbk + (size_t)bi * 64 + ch * 16);
    float4* dp = (float4*)(zq + ((size_t)blockIdx.x * 64 + vs) * 64 + ch * 16);
#pragma unroll
    for (int q = 0; q < 4; q++) dp[q] = sp[q];
}

// zq (fp32 NCHW) -> channel-last bf16 [n][y][x][64]
__global__ __launch_bounds__(256) void zqt_k(
    const float* __restrict__ zq, u16* __restrict__ out)
{
    __shared__ float t[64][65];
    const int tid = threadIdx.x;
    const int n = blockIdx.x >> 6, y = blockIdx.x & 63;
    for (int idx = tid; idx < 4096; idx += 256) {
        int xx = idx & 63, ci = idx >> 6;
        t[ci][xx] = zq[(((size_t)n * 64 + ci) * 64 + y) * 64 + xx];
    }
    __syncthreads();
    for (int idx = tid; idx < 4096; idx += 256) {
        int ci = idx & 63, xx = idx >> 6;
        out[(((size_t)n * 64 + y) * 64 + xx) * 64 + ci] = f2bf(t[ci][xx]);
    }
}

// ---------------------------------------------------------------------------
extern "C" void kernel_launch(void* const* d_in, const int* in_sizes, int n_in,
                              void* d_out, int out_size, void* d_ws, size_t ws_size,
                              hipStream_t stream)
{
    (void)in_sizes; (void)n_in; (void)out_size; (void)ws_size;

    const float* x   = (const float*)d_in[0];
    const float* ew1 = (const float*)d_in[1];
    const float* eb1 = (const float*)d_in[2];
    const float* ew2 = (const float*)d_in[3];
    const float* eb2 = (const float*)d_in[4];
    const float* ew3 = (const float*)d_in[5];
    const float* eb3 = (const float*)d_in[6];
    const float* cbk = (const float*)d_in[7];
    const float* dw1 = (const float*)d_in[8];
    const float* db1 = (const float*)d_in[9];
    const float* dw2 = (const float*)d_in[10];
    const float* db2 = (const float*)d_in[11];
    const float* dw3 = (const float*)d_in[12];
    const float* db3 = (const float*)d_in[13];

    // region0 (134.2 MB): P (enc1 out) -> zq_cl -> A2 (time-multiplexed)
    u16* P    = (u16*)d_ws;
    u16* ZQCL = P;
    u16* A2   = P;
    u16* B = (u16*)((char*)d_ws + 134217728);         // 33.5 MB region
    u16* XCL = B;                                     // x_cl 17 MB (dead by enc2)
    u16* Wg2 = (u16*)((char*)d_ws + 167772160);       // 262144
    u16* Wg3 = Wg2 + 262144;                          // 73728
    u16* Wg4 = Wg3 + 73728;                           // 73728
    u16* Wg5 = Wg4 + 73728;                           // 262144
    u16* Wg6 = Wg5 + 262144;                          // 32768
    u16* CB  = Wg6 + 32768;                           // 32768
    u16* Wg1 = CB + 32768;                            // 8192 (enc1)
    float* CNg = (float*)(Wg1 + 8192);                // 512

    float* xr = (float*)d_out;
    float* ze = xr + (size_t)32 * 3 * 256 * 256;
    float* zq = ze + (size_t)32 * 64 * 64 * 64;

    g_enc1<<<32, 256, 0, stream>>>(ew1, Wg1);
    g_enc2<<<1024, 256, 0, stream>>>(ew2, Wg2);
    g_k3<<<288, 256, 0, stream>>>(ew3, Wg3, 128, 64);
    g_k3<<<288, 256, 0, stream>>>(dw1, Wg4, 64, 128);
    g_dec2<<<1024, 256, 0, stream>>>(dw2, Wg5);
    g_dec3<<<128, 256, 0, stream>>>(dw3, Wg6);
    g_cbk<<<128, 256, 0, stream>>>(cbk, CB, CNg);

    // x -> padded channel-last bf16
    xcl_k<<<32 * 258, 256, 0, stream>>>(x, XCL);
    // enc1 (MFMA) -> P (channel-last parity planes), relu
    enc1m_k<<<32 * 128, 256, 0, stream>>>(XCL, Wg1, eb1, P);
    // enc2: 4 planes k2 -> B (CL, relu)
    conv_mx2<2, 2, 4, 1, 0><<<32 * 32, 256, 0, stream>>>(P, Wg2, eb2, B, 128, 128);
    // enc3: k3 -> ze (fp32 NCHW)
    conv_mx2<3, 3, 1, 2, 1><<<16 * 32, 256, 0, stream>>>(B, Wg3, eb3, ze, 128, 64);
    // VQ
    vqm_k<<<2048, 256, 0, stream>>>(ze, CB, CNg, cbk, zq);
    // zq -> channel-last bf16
    zqt_k<<<2048, 256, 0, stream>>>(zq, ZQCL);
    // dec1: k3 -> B (CL, relu)
    conv_mx2<3, 3, 1, 1, 0><<<32 * 32, 256, 0, stream>>>(ZQCL, Wg4, db1, B, 64, 128);
    // deconv2: k2 x 4 parities -> A2 (CL, relu)
    conv_mx2<2, 2, 1, 1, 2><<<dim3(32 * 32, 4), 256, 0, stream>>>(B, Wg5, db2, A2, 128, 128);
    // deconv3 -> x_recon
    dec3_k<<<1024, 256, 0, stream>>>(A2, Wg6, db3, xr);
}

// Round 8
// 590.227 us; speedup vs baseline: 17.4123x; 1.2399x over previous
//
#include <hip/hip_runtime.h>
#include <hip/hip_bf16.h>

// VQ-VAE forward. R8: dec3 rewrite — parity-packed M-rows (12/16 used),
// tap-by-offset weights, rolling 3-row B window. Rest from R7.

typedef unsigned short u16;
typedef unsigned int u32;
typedef unsigned long long u64;
typedef __attribute__((ext_vector_type(8))) short short8;
typedef __attribute__((ext_vector_type(4))) float f32x4;

__device__ __forceinline__ float bf2f(u16 u) {
    union { u32 i; float f; } x; x.i = ((u32)u) << 16; return x.f;
}
__device__ __forceinline__ u16 f2bf(float f) {
    __hip_bfloat16 h = __float2bfloat16(f);
    return *reinterpret_cast<u16*>(&h);
}

// ---------------------------------------------------------------------------
// Weight gathers (bf16, MFMA layouts).
// ---------------------------------------------------------------------------
__global__ void g_k3(const float* __restrict__ w, u16* __restrict__ wg,
                     int CIN, int COUT)   // OIHW k3: wg[(s*COUT+co)*CIN+ci]
{
    int idx = blockIdx.x * 256 + threadIdx.x;
    if (idx >= 9 * CIN * COUT) return;
    int ci = idx % CIN;
    int co = (idx / CIN) % COUT;
    int s  = idx / (CIN * COUT);
    wg[idx] = f2bf(w[(co * CIN + ci) * 9 + s]);
}

__global__ void g_enc2(const float* __restrict__ w, u16* __restrict__ wg)
{
    int idx = blockIdx.x * 256 + threadIdx.x;   // p(4) s(4) co(128) ci(128)
    int ci = idx & 127, co = (idx >> 7) & 127, s = (idx >> 14) & 3, p = idx >> 16;
    int a = p >> 1, b = p & 1, j = s >> 1, i = s & 1;
    int ky = (1 - a) + 2 * j, kx = (1 - b) + 2 * i;
    wg[idx] = f2bf(w[((co << 7 | ci) << 4) + ky * 4 + kx]);
}

__global__ void g_dec2(const float* __restrict__ w, u16* __restrict__ wg)
{
    int idx = blockIdx.x * 256 + threadIdx.x;   // p(4) s(4) co(128) ci(128)
    int ci = idx & 127, co = (idx >> 7) & 127, s = (idx >> 14) & 3, p = idx >> 16;
    int py = p >> 1, px = p & 1, j = s >> 1, i = s & 1;
    wg[idx] = f2bf(w[((ci << 7 | co) << 4) + (3 - (py + 2 * j)) * 4 + (3 - (px + 2 * i))]);
}

// dec3 parity-packed: wg[(t*16 + row)*128 + ci], t=(dy+1)*3+(dx+1),
// row = p*3+co (p<4, co<3; rows 12..15 zero). Entry nonzero iff
// a=dy+1-py in {0,1} and b=dx+1-px in {0,1}; then w = dw3 IOHW flipped.
__global__ void g_dec3m(const float* __restrict__ w, u16* __restrict__ wg)
{
    int idx = blockIdx.x * 256 + threadIdx.x;   // 9*16*128 = 18432
    if (idx >= 18432) return;
    int ci  = idx & 127;
    int row = (idx >> 7) & 15;
    int t   = idx >> 11;
    int dy = t / 3 - 1, dx = t % 3 - 1;
    float v = 0.f;
    if (row < 12) {
        int p = row / 3, co = row % 3;
        int py = p >> 1, px = p & 1;
        int a = dy + 1 - py, b2 = dx + 1 - px;
        if (a >= 0 && a <= 1 && b2 >= 0 && b2 <= 1)
            v = w[((ci * 3 + co) * 4 + (3 - (py + 2 * a))) * 4 + (3 - (px + 2 * b2))];
    }
    wg[idx] = f2bf(v);
}

// enc1 weights: wg[co*64 + ky*16 + kx*4 + ci] (ci 3->4 zero pad), OIHW k4.
__global__ void g_enc1(const float* __restrict__ w, u16* __restrict__ wg)
{
    int idx = blockIdx.x * 256 + threadIdx.x;   // 128*64 = 8192
    if (idx >= 8192) return;
    int ci = idx & 3, kx = (idx >> 2) & 3, ky = (idx >> 4) & 3, co = idx >> 6;
    float v = 0.f;
    if (ci < 3) v = w[((co * 3 + ci) * 4 + ky) * 4 + kx];
    wg[idx] = f2bf(v);
}

__global__ void g_cbk(const float* __restrict__ cbk, u16* __restrict__ cb,
                      float* __restrict__ cn)
{
    int idx = blockIdx.x * 256 + threadIdx.x;   // 32768
    if (idx >= 32768) return;
    cb[idx] = f2bf(cbk[idx]);
    if (idx < 512) {
        float s = 0.f;
        const float* r = cbk + idx * 64;
        for (int i = 0; i < 64; i++) s += r[i] * r[i];
        cn[idx] = s;
    }
}

// x (fp32 NCHW) -> x_cl[n][258][258][4] bf16, zero-padded halo + 4th channel.
__global__ __launch_bounds__(256) void xcl_k(
    const float* __restrict__ x, u16* __restrict__ xcl)
{
    const int y = blockIdx.x % 258, n = blockIdx.x / 258;
    const int gy = y - 1;
    for (int xx = threadIdx.x; xx < 258; xx += 256) {
        const int gx = xx - 1;
        u16 pk[4] = {0, 0, 0, 0};
        if (gy >= 0 && gy < 256 && gx >= 0 && gx < 256) {
            const size_t base = ((size_t)n * 3 * 256 + gy) * 256 + gx;
            pk[0] = f2bf(x[base]);
            pk[1] = f2bf(x[base + 65536]);
            pk[2] = f2bf(x[base + 131072]);
        }
        *(u64*)(xcl + ((size_t)(n * 258 + y) * 258 + xx) * 4) = *(const u64*)pk;
    }
}

// ---------------------------------------------------------------------------
// enc1 via MFMA (R7, validated).
// ---------------------------------------------------------------------------
__global__ __launch_bounds__(256) void enc1m_k(
    const u16* __restrict__ xcl, const u16* __restrict__ wg,
    const float* __restrict__ bias, u16* __restrict__ P)
{
    const int tid = threadIdx.x;
    const int l = tid & 63, w = tid >> 6;
    const int ln = l & 15, kg = l >> 4;
    const int px = w >> 1, half = w & 1;

    const int oy = blockIdx.x & 127;
    const int n  = blockIdx.x >> 7;
    const int p  = (oy & 1) * 2 + px;
    const int yy = oy >> 1;

    short8 af[8][2];
#pragma unroll
    for (int u = 0; u < 8; u++)
#pragma unroll
        for (int s = 0; s < 2; s++)
            af[u][s] = *(const short8*)(wg + ((u * 16 + ln) << 6) + s * 32 + 8 * kg);

    const u16* xn = xcl + (size_t)n * 258 * 258 * 4;
    const int r0 = 2 * oy;

#pragma unroll
    for (int t = 0; t < 2; t++) {
        const int xq = half * 32 + t * 16 + ln;
        const int ox = px + 2 * xq;

        short8 bf[2];
#pragma unroll
        for (int s = 0; s < 2; s++) {
            const int row = r0 + 2 * s + (kg >> 1);
            bf[s] = *(const short8*)(xn + ((size_t)row * 258 + 2 * ox) * 4
                                     + (kg & 1) * 8);
        }

        f32x4 acc[8];
#pragma unroll
        for (int u = 0; u < 8; u++) acc[u] = (f32x4){0.f, 0.f, 0.f, 0.f};
#pragma unroll
        for (int u = 0; u < 8; u++) {
            acc[u] = __builtin_amdgcn_mfma_f32_16x16x32_bf16(af[u][0], bf[0], acc[u], 0, 0, 0);
            acc[u] = __builtin_amdgcn_mfma_f32_16x16x32_bf16(af[u][1], bf[1], acc[u], 0, 0, 0);
        }

#pragma unroll
        for (int u = 0; u < 8; u++) {
            const int cobase = u * 16 + 4 * kg;
            u16 pk[4];
#pragma unroll
            for (int r = 0; r < 4; r++)
                pk[r] = f2bf(fmaxf(acc[u][r] + bias[cobase + r], 0.f));
            *(u64*)(P + ((((size_t)(n * 4 + p) * 64 + yy) * 64 + xq) << 7) + cobase)
                = *(const u64*)pk;
        }
    }
}

// ---------------------------------------------------------------------------
// conv_mx2 (R6, validated): stride-1 MFMA conv on 64x64 channel-last planes.
// ---------------------------------------------------------------------------
template<int J, int I, int NP, int SY, int OUTM>
__global__ __launch_bounds__(256) void conv_mx2(
    const u16* __restrict__ x, const u16* __restrict__ wg,
    const float* __restrict__ bias, void* __restrict__ yv,
    int CIN, int COUT)
{
    constexpr int RS = 2 * SY + 2;
    __shared__ u16 XL[RS * 68 * 40];
    constexpr int NCW = 4 / SY;

    const int tid = threadIdx.x;
    const int l = tid & 63, wv = tid >> 6;
    const int kg = l >> 4, ln = l & 15;
    const int cw = wv % NCW, g = wv / NCW;

    int b = blockIdx.x;
    constexpr int TILES = 64 / (2 * SY);
    const int tile = b % TILES;  b /= TILES;
    const int n = b;
    const int OY0 = tile * (2 * SY);
    const int pc = (OUTM == 2) ? blockIdx.y : 0;

    f32x4 acc[2][8];
#pragma unroll
    for (int u = 0; u < 2; u++)
#pragma unroll
        for (int t = 0; t < 8; t++) acc[u][t] = (f32x4){0.f, 0.f, 0.f, 0.f};

    const u16* xn = x + (size_t)n * NP * CIN * 4096;
    const int co0 = cw * 32 + ln;

    for (int p = 0; p < NP; p++) {
        int dy0, dx0;
        const u16* wgp;
        if (OUTM == 2) {
            dy0 = (pc >> 1) - 1; dx0 = (pc & 1) - 1;
            wgp = wg + (size_t)pc * J * I * COUT * CIN;
        } else if (NP == 4) {
            dy0 = -(p >> 1); dx0 = -(p & 1);
            wgp = wg + (size_t)p * J * I * COUT * CIN;
        } else {
            dy0 = -1; dx0 = -1; wgp = wg;
        }
        const u16* xp = xn + (size_t)p * CIN * 4096;

        for (int ci0 = 0; ci0 < CIN; ci0 += 32) {
            __syncthreads();
            constexpr int TASKS = RS * 68 * 4;
            for (int idx = tid; idx < TASKS; idx += 256) {
                const int q  = idx & 3;
                const int cc = (idx >> 2) % 68;
                const int r  = (idx >> 2) / 68;
                const int gr = OY0 - 1 + r;
                const int gx = cc - 1;
                short8 v = (short8){0, 0, 0, 0, 0, 0, 0, 0};
                if (gr >= 0 && gr < 64 && gx >= 0 && gx < 64)
                    v = *(const short8*)(xp + (size_t)(gr * 64 + gx) * CIN
                                         + ci0 + 8 * q);
                *(short8*)(XL + (r * 68 + cc) * 40 + 8 * q) = v;
            }
            __syncthreads();

#define TAP_ROW(jv)                                                          \
            {                                                                \
                short8 wf0[I], wf1[I];                                       \
                _Pragma("unroll")                                            \
                for (int i = 0; i < I; i++) {                                \
                    const size_t wb = ((size_t)((jv) * I + i) * COUT + co0)  \
                                      * CIN + ci0 + 8 * kg;                  \
                    wf0[i] = *(const short8*)(wgp + wb);                     \
                    wf1[i] = *(const short8*)(wgp + wb + (size_t)16 * CIN);  \
                }                                                            \
                _Pragma("unroll")                                            \
                for (int i = 0; i < I; i++) {                                \
                    _Pragma("unroll")                                        \
                    for (int t = 0; t < 8; t++) {                            \
                        const int rf = (t >> 2) + 2 * g + dy0 + 1 + (jv);    \
                        const int cf = (t & 3) * 16 + ln + dx0 + 1 + i;      \
                        const short8 bf = *(const short8*)(                  \
                            XL + (rf * 68 + cf) * 40 + 8 * kg);              \
                        acc[0][t] = __builtin_amdgcn_mfma_f32_16x16x32_bf16( \
                            wf0[i], bf, acc[0][t], 0, 0, 0);                 \
                        acc[1][t] = __builtin_amdgcn_mfma_f32_16x16x32_bf16( \
                            wf1[i], bf, acc[1][t], 0, 0, 0);                 \
                    }                                                        \
                }                                                            \
            }

            if constexpr (J == 2) {
                TAP_ROW(0); TAP_ROW(1);
            } else {
#pragma unroll 1
                for (int j = 0; j < J; j++) TAP_ROW(j);
            }
#undef TAP_ROW
        }
    }

#pragma unroll
    for (int u = 0; u < 2; u++) {
        const int cob = cw * 32 + u * 16 + 4 * kg;
#pragma unroll
        for (int t = 0; t < 8; t++) {
            const int oy = OY0 + 2 * g + (t >> 2);
            const int ox = (t & 3) * 16 + ln;
            if constexpr (OUTM == 1) {
                float* out = (float*)yv;
#pragma unroll
                for (int rr = 0; rr < 4; rr++)
                    out[(((size_t)n * COUT + cob + rr) * 64 + oy) * 64 + ox]
                        = acc[u][t][rr] + bias[cob + rr];
            } else {
                u16 pk[4];
#pragma unroll
                for (int rr = 0; rr < 4; rr++)
                    pk[rr] = f2bf(fmaxf(acc[u][t][rr] + bias[cob + rr], 0.f));
                if constexpr (OUTM == 0) {
                    *(u64*)((u16*)yv + ((size_t)(n * 64 + oy) * 64 + ox) * COUT
                            + cob) = *(const u64*)pk;
                } else {
                    const int OY = 2 * oy + (pc >> 1), OX = 2 * ox + (pc & 1);
                    *(u64*)((u16*)yv + ((size_t)(n * 128 + OY) * 128 + OX) * 128
                            + cob) = *(const u64*)pk;
                }
            }
        }
    }
}

// ---------------------------------------------------------------------------
// dec3m: deconv3 via parity-packed MFMA. A2[n][y][x][128] bf16 CL.
// A = W_(dy,dx)[row=p*3+co][ci] (12/16 rows), B = x row window (rolling).
// Per wave: 8 m-rows; 9 MFMA/row/ks; kg<3 lanes store 4 rows each.
// ---------------------------------------------------------------------------
__global__ __launch_bounds__(256) void dec3m_k(
    const u16* __restrict__ A2, const u16* __restrict__ wg,
    const float* __restrict__ bias, float* __restrict__ out)
{
    const int tid = threadIdx.x;
    const int l = tid & 63, wvi = tid >> 6;
    const int ln = l & 15, kg = l >> 4;

    int b = blockIdx.x;
    const int mxT = b & 7;  b >>= 3;
    const int myT = b & 3;  b >>= 2;
    const int n = b;
    const int X0 = mxT * 16;
    const int MY0 = myT * 32 + wvi * 8;
    const int xx = X0 + ln;

    const short8 z8 = (short8){0, 0, 0, 0, 0, 0, 0, 0};

    f32x4 acc[8];
#pragma unroll
    for (int m = 0; m < 8; m++) acc[m] = (f32x4){0.f, 0.f, 0.f, 0.f};

    // precomputed per-lane x info for the 3 shifts
    int xoff[3]; bool xok[3];
#pragma unroll
    for (int sh = 0; sh < 3; sh++) {
        const int xv = xx + sh - 1;
        xok[sh] = (xv >= 0) & (xv < 128);
        xoff[sh] = (xok[sh] ? xv : 0) << 7;       // *128 ci
    }

    for (int ks = 0; ks < 4; ks++) {
        const int cio = ks * 32 + 8 * kg;

        short8 at[9];
#pragma unroll
        for (int t = 0; t < 9; t++)
            at[t] = *(const short8*)(wg + (((size_t)t * 16 + ln) << 7) + cio);

        short8 B[10][3];
#pragma unroll
        for (int r = 0; r < 10; r++) {
            const int yy = MY0 - 1 + r;
            const bool yok = (yy >= 0) & (yy < 128);
            const size_t rowb = ((size_t)(n * 128 + (yok ? yy : 0)) << 7 << 7);
#pragma unroll
            for (int sh = 0; sh < 3; sh++) {
                short8 v = *(const short8*)(A2 + rowb + xoff[sh] + cio);
                B[r][sh] = (yok & xok[sh]) ? v : z8;
            }
            if (r >= 2) {
                const int m = r - 2;
#pragma unroll
                for (int rr = 0; rr < 3; rr++)
#pragma unroll
                    for (int sh = 0; sh < 3; sh++)
                        acc[m] = __builtin_amdgcn_mfma_f32_16x16x32_bf16(
                            at[rr * 3 + sh], B[m + rr][sh], acc[m], 0, 0, 0);
            }
        }
    }

    if (kg < 3) {
#pragma unroll
        for (int m = 0; m < 8; m++) {
            const int my = MY0 + m;
#pragma unroll
            for (int rr = 0; rr < 4; rr++) {
                const int row = 4 * kg + rr;          // 0..11
                const int p = row / 3, co = row % 3;
                const int oy = 2 * my + (p >> 1);
                const int ox = 2 * xx + (p & 1);
                out[(((size_t)(n * 3 + co)) << 16) + oy * 256 + ox]
                    = acc[m][rr] + bias[co];
            }
        }
    }
}

// ---------------------------------------------------------------------------
// VQ via MFMA GEMM (R5, validated).
// ---------------------------------------------------------------------------
__global__ __launch_bounds__(256) void vqm_k(
    const float* __restrict__ ze, const u16* __restrict__ cb,
    const float* __restrict__ cn, const float* __restrict__ cbk,
    float* __restrict__ zq)
{
    __shared__ float CN[512];
    __shared__ int IDX[64];
    const int tid = threadIdx.x;
    const int l = tid & 63, wvi = tid >> 6;
    const int ln = l & 15, kg = l >> 4;

    for (int i = tid; i < 512; i += 256) CN[i] = cn[i];
    __syncthreads();

    const int V0 = blockIdx.x * 64 + wvi * 16;

    short8 az[2];
#pragma unroll
    for (int ks = 0; ks < 2; ks++) {
        const float* zp = ze + (size_t)(V0 + ln) * 64 + ks * 32 + 8 * kg;
        short8 t;
#pragma unroll
        for (int j = 0; j < 8; j++) t[j] = (short)f2bf(zp[j]);
        az[ks] = t;
    }

    float bval[4] = {3.4e38f, 3.4e38f, 3.4e38f, 3.4e38f};
    int bidx[4] = {0, 0, 0, 0};
    for (int nt = 0; nt < 32; nt++) {
        const int code = nt * 16 + ln;
        const short8 b0 = *(const short8*)(cb + (size_t)code * 64 + 8 * kg);
        const short8 b1 = *(const short8*)(cb + (size_t)code * 64 + 32 + 8 * kg);
        f32x4 d = (f32x4){0.f, 0.f, 0.f, 0.f};
        d = __builtin_amdgcn_mfma_f32_16x16x32_bf16(az[0], b0, d, 0, 0, 0);
        d = __builtin_amdgcn_mfma_f32_16x16x32_bf16(az[1], b1, d, 0, 0, 0);
        const float cnv = CN[code];
#pragma unroll
        for (int r = 0; r < 4; r++) {
            const float dist = cnv - 2.f * d[r];
            if (dist < bval[r]) { bval[r] = dist; bidx[r] = code; }
        }
    }
#pragma unroll
    for (int off = 1; off < 16; off <<= 1) {
#pragma unroll
        for (int r = 0; r < 4; r++) {
            const float ov = __shfl_xor(bval[r], off);
            const int oi = __shfl_xor(bidx[r], off);
            if (ov < bval[r] || (ov == bval[r] && oi < bidx[r])) {
                bval[r] = ov; bidx[r] = oi;
            }
        }
    }
    if (ln == 0) {
#pragma unroll
        for (int r = 0; r < 4; r++) IDX[wvi * 16 + 4 * kg + r] = bidx[r];
    }
    __syncthreads();

    const int vs = tid >> 2, ch = tid & 3;
    const int bi = IDX[vs];
    const float4* sp = (const float4*)(cbk + (size_t)bi * 64 + ch * 16);
    float4* dp = (float4*)(zq + ((size_t)blockIdx.x * 64 + vs) * 64 + ch * 16);
#pragma unroll
    for (int q = 0; q < 4; q++) dp[q] = sp[q];
}

// zq (fp32 NCHW) -> channel-last bf16 [n][y][x][64]
__global__ __launch_bounds__(256) void zqt_k(
    const float* __restrict__ zq, u16* __restrict__ out)
{
    __shared__ float t[64][65];
    const int tid = threadIdx.x;
    const int n = blockIdx.x >> 6, y = blockIdx.x & 63;
    for (int idx = tid; idx < 4096; idx += 256) {
        int xx = idx & 63, ci = idx >> 6;
        t[ci][xx] = zq[(((size_t)n * 64 + ci) * 64 + y) * 64 + xx];
    }
    __syncthreads();
    for (int idx = tid; idx < 4096; idx += 256) {
        int ci = idx & 63, xx = idx >> 6;
        out[(((size_t)n * 64 + y) * 64 + xx) * 64 + ci] = f2bf(t[ci][xx]);
    }
}

// ---------------------------------------------------------------------------
extern "C" void kernel_launch(void* const* d_in, const int* in_sizes, int n_in,
                              void* d_out, int out_size, void* d_ws, size_t ws_size,
                              hipStream_t stream)
{
    (void)in_sizes; (void)n_in; (void)out_size; (void)ws_size;

    const float* x   = (const float*)d_in[0];
    const float* ew1 = (const float*)d_in[1];
    const float* eb1 = (const float*)d_in[2];
    const float* ew2 = (const float*)d_in[3];
    const float* eb2 = (const float*)d_in[4];
    const float* ew3 = (const float*)d_in[5];
    const float* eb3 = (const float*)d_in[6];
    const float* cbk = (const float*)d_in[7];
    const float* dw1 = (const float*)d_in[8];
    const float* db1 = (const float*)d_in[9];
    const float* dw2 = (const float*)d_in[10];
    const float* db2 = (const float*)d_in[11];
    const float* dw3 = (const float*)d_in[12];
    const float* db3 = (const float*)d_in[13];

    u16* P    = (u16*)d_ws;
    u16* ZQCL = P;
    u16* A2   = P;
    u16* B = (u16*)((char*)d_ws + 134217728);
    u16* XCL = B;
    u16* Wg2 = (u16*)((char*)d_ws + 167772160);       // 262144
    u16* Wg3 = Wg2 + 262144;                          // 73728
    u16* Wg4 = Wg3 + 73728;                           // 73728
    u16* Wg5 = Wg4 + 73728;                           // 262144
    u16* Wg6 = Wg5 + 262144;                          // 18432 (dec3m)
    u16* CB  = Wg6 + 32768;                           // 32768
    u16* Wg1 = CB + 32768;                            // 8192
    float* CNg = (float*)(Wg1 + 8192);                // 512

    float* xr = (float*)d_out;
    float* ze = xr + (size_t)32 * 3 * 256 * 256;
    float* zq = ze + (size_t)32 * 64 * 64 * 64;

    g_enc1<<<32, 256, 0, stream>>>(ew1, Wg1);
    g_enc2<<<1024, 256, 0, stream>>>(ew2, Wg2);
    g_k3<<<288, 256, 0, stream>>>(ew3, Wg3, 128, 64);
    g_k3<<<288, 256, 0, stream>>>(dw1, Wg4, 64, 128);
    g_dec2<<<1024, 256, 0, stream>>>(dw2, Wg5);
    g_dec3m<<<72, 256, 0, stream>>>(dw3, Wg6);
    g_cbk<<<128, 256, 0, stream>>>(cbk, CB, CNg);

    xcl_k<<<32 * 258, 256, 0, stream>>>(x, XCL);
    enc1m_k<<<32 * 128, 256, 0, stream>>>(XCL, Wg1, eb1, P);
    conv_mx2<2, 2, 4, 1, 0><<<32 * 32, 256, 0, stream>>>(P, Wg2, eb2, B, 128, 128);
    conv_mx2<3, 3, 1, 2, 1><<<16 * 32, 256, 0, stream>>>(B, Wg3, eb3, ze, 128, 64);
    vqm_k<<<2048, 256, 0, stream>>>(ze, CB, CNg, cbk, zq);
    zqt_k<<<2048, 256, 0, stream>>>(zq, ZQCL);
    conv_mx2<3, 3, 1, 1, 0><<<32 * 32, 256, 0, stream>>>(ZQCL, Wg4, db1, B, 64, 128);
    conv_mx2<2, 2, 1, 1, 2><<<dim3(32 * 32, 4), 256, 0, stream>>>(B, Wg5, db2, A2, 128, 128);
    dec3m_k<<<1024, 256, 0, stream>>>(A2, Wg6, db3, xr);
}

// Round 9
// 572.058 us; speedup vs baseline: 17.9653x; 1.0318x over previous
//
#include <hip/hip_runtime.h>
#include <hip/hip_bf16.h>

// VQ-VAE forward. R9: conv_mx3 — 8-wave blocks (NCW co-waves x G row-groups),
// register-prefetch staging (issue-early/write-late), halo 1.5x/1.25x.
// enc1m/dec3m/vqm/zqt/xcl from R7/R8 (validated).

typedef unsigned short u16;
typedef unsigned int u32;
typedef unsigned long long u64;
typedef __attribute__((ext_vector_type(8))) short short8;
typedef __attribute__((ext_vector_type(4))) float f32x4;

__device__ __forceinline__ float bf2f(u16 u) {
    union { u32 i; float f; } x; x.i = ((u32)u) << 16; return x.f;
}
__device__ __forceinline__ u16 f2bf(float f) {
    __hip_bfloat16 h = __float2bfloat16(f);
    return *reinterpret_cast<u16*>(&h);
}

// ---------------------------------------------------------------------------
// Weight gathers (bf16, MFMA layouts).
// ---------------------------------------------------------------------------
__global__ void g_k3(const float* __restrict__ w, u16* __restrict__ wg,
                     int CIN, int COUT)   // OIHW k3: wg[(s*COUT+co)*CIN+ci]
{
    int idx = blockIdx.x * 256 + threadIdx.x;
    if (idx >= 9 * CIN * COUT) return;
    int ci = idx % CIN;
    int co = (idx / CIN) % COUT;
    int s  = idx / (CIN * COUT);
    wg[idx] = f2bf(w[(co * CIN + ci) * 9 + s]);
}

__global__ void g_enc2(const float* __restrict__ w, u16* __restrict__ wg)
{
    int idx = blockIdx.x * 256 + threadIdx.x;   // p(4) s(4) co(128) ci(128)
    int ci = idx & 127, co = (idx >> 7) & 127, s = (idx >> 14) & 3, p = idx >> 16;
    int a = p >> 1, b = p & 1, j = s >> 1, i = s & 1;
    int ky = (1 - a) + 2 * j, kx = (1 - b) + 2 * i;
    wg[idx] = f2bf(w[((co << 7 | ci) << 4) + ky * 4 + kx]);
}

__global__ void g_dec2(const float* __restrict__ w, u16* __restrict__ wg)
{
    int idx = blockIdx.x * 256 + threadIdx.x;   // p(4) s(4) co(128) ci(128)
    int ci = idx & 127, co = (idx >> 7) & 127, s = (idx >> 14) & 3, p = idx >> 16;
    int py = p >> 1, px = p & 1, j = s >> 1, i = s & 1;
    wg[idx] = f2bf(w[((ci << 7 | co) << 4) + (3 - (py + 2 * j)) * 4 + (3 - (px + 2 * i))]);
}

// dec3 parity-packed (R8, validated)
__global__ void g_dec3m(const float* __restrict__ w, u16* __restrict__ wg)
{
    int idx = blockIdx.x * 256 + threadIdx.x;   // 9*16*128 = 18432
    if (idx >= 18432) return;
    int ci  = idx & 127;
    int row = (idx >> 7) & 15;
    int t   = idx >> 11;
    int dy = t / 3 - 1, dx = t % 3 - 1;
    float v = 0.f;
    if (row < 12) {
        int p = row / 3, co = row % 3;
        int py = p >> 1, px = p & 1;
        int a = dy + 1 - py, b2 = dx + 1 - px;
        if (a >= 0 && a <= 1 && b2 >= 0 && b2 <= 1)
            v = w[((ci * 3 + co) * 4 + (3 - (py + 2 * a))) * 4 + (3 - (px + 2 * b2))];
    }
    wg[idx] = f2bf(v);
}

__global__ void g_enc1(const float* __restrict__ w, u16* __restrict__ wg)
{
    int idx = blockIdx.x * 256 + threadIdx.x;   // 128*64 = 8192
    if (idx >= 8192) return;
    int ci = idx & 3, kx = (idx >> 2) & 3, ky = (idx >> 4) & 3, co = idx >> 6;
    float v = 0.f;
    if (ci < 3) v = w[((co * 3 + ci) * 4 + ky) * 4 + kx];
    wg[idx] = f2bf(v);
}

__global__ void g_cbk(const float* __restrict__ cbk, u16* __restrict__ cb,
                      float* __restrict__ cn)
{
    int idx = blockIdx.x * 256 + threadIdx.x;   // 32768
    if (idx >= 32768) return;
    cb[idx] = f2bf(cbk[idx]);
    if (idx < 512) {
        float s = 0.f;
        const float* r = cbk + idx * 64;
        for (int i = 0; i < 64; i++) s += r[i] * r[i];
        cn[idx] = s;
    }
}

// x (fp32 NCHW) -> x_cl[n][258][258][4] bf16
__global__ __launch_bounds__(256) void xcl_k(
    const float* __restrict__ x, u16* __restrict__ xcl)
{
    const int y = blockIdx.x % 258, n = blockIdx.x / 258;
    const int gy = y - 1;
    for (int xx = threadIdx.x; xx < 258; xx += 256) {
        const int gx = xx - 1;
        u16 pk[4] = {0, 0, 0, 0};
        if (gy >= 0 && gy < 256 && gx >= 0 && gx < 256) {
            const size_t base = ((size_t)n * 3 * 256 + gy) * 256 + gx;
            pk[0] = f2bf(x[base]);
            pk[1] = f2bf(x[base + 65536]);
            pk[2] = f2bf(x[base + 131072]);
        }
        *(u64*)(xcl + ((size_t)(n * 258 + y) * 258 + xx) * 4) = *(const u64*)pk;
    }
}

// ---------------------------------------------------------------------------
// enc1 via MFMA (R7, validated).
// ---------------------------------------------------------------------------
__global__ __launch_bounds__(256) void enc1m_k(
    const u16* __restrict__ xcl, const u16* __restrict__ wg,
    const float* __restrict__ bias, u16* __restrict__ P)
{
    const int tid = threadIdx.x;
    const int l = tid & 63, w = tid >> 6;
    const int ln = l & 15, kg = l >> 4;
    const int px = w >> 1, half = w & 1;

    const int oy = blockIdx.x & 127;
    const int n  = blockIdx.x >> 7;
    const int p  = (oy & 1) * 2 + px;
    const int yy = oy >> 1;

    short8 af[8][2];
#pragma unroll
    for (int u = 0; u < 8; u++)
#pragma unroll
        for (int s = 0; s < 2; s++)
            af[u][s] = *(const short8*)(wg + ((u * 16 + ln) << 6) + s * 32 + 8 * kg);

    const u16* xn = xcl + (size_t)n * 258 * 258 * 4;
    const int r0 = 2 * oy;

#pragma unroll
    for (int t = 0; t < 2; t++) {
        const int xq = half * 32 + t * 16 + ln;
        const int ox = px + 2 * xq;

        short8 bf[2];
#pragma unroll
        for (int s = 0; s < 2; s++) {
            const int row = r0 + 2 * s + (kg >> 1);
            bf[s] = *(const short8*)(xn + ((size_t)row * 258 + 2 * ox) * 4
                                     + (kg & 1) * 8);
        }

        f32x4 acc[8];
#pragma unroll
        for (int u = 0; u < 8; u++) acc[u] = (f32x4){0.f, 0.f, 0.f, 0.f};
#pragma unroll
        for (int u = 0; u < 8; u++) {
            acc[u] = __builtin_amdgcn_mfma_f32_16x16x32_bf16(af[u][0], bf[0], acc[u], 0, 0, 0);
            acc[u] = __builtin_amdgcn_mfma_f32_16x16x32_bf16(af[u][1], bf[1], acc[u], 0, 0, 0);
        }

#pragma unroll
        for (int u = 0; u < 8; u++) {
            const int cobase = u * 16 + 4 * kg;
            u16 pk[4];
#pragma unroll
            for (int r = 0; r < 4; r++)
                pk[r] = f2bf(fmaxf(acc[u][r] + bias[cobase + r], 0.f));
            *(u64*)(P + ((((size_t)(n * 4 + p) * 64 + yy) * 64 + xq) << 7) + cobase)
                = *(const u64*)pk;
        }
    }
}

// ---------------------------------------------------------------------------
// conv_mx3: stride-1 MFMA conv, 8 waves (NCW co-waves x G=8/NCW row-groups),
// 2G output rows per block, register-prefetch staging (T14).
// OUTM: 0 = bf16 CL [64][64][COUT] relu; 1 = fp32 NCHW; 2 = deconv parity CL.
// ---------------------------------------------------------------------------
template<int J, int I, int NP, int NCW, int CI, int OUTM>
__global__ __launch_bounds__(512) void conv_mx3(
    const u16* __restrict__ x, const u16* __restrict__ wg,
    const float* __restrict__ bias, void* __restrict__ yv,
    int COUT)
{
    constexpr int G = 8 / NCW;
    constexpr int RS = 2 * G + 2;
    constexpr int TASKS = RS * 68 * 4;
    constexpr int SLOTS = (TASKS + 511) / 512;
    constexpr int CHP = CI / 32;
    constexpr int NCHUNK = NP * CHP;
    __shared__ u16 XL[RS * 68 * 40];

    const int tid = threadIdx.x;
    const int l = tid & 63, wv = tid >> 6;
    const int kg = l >> 4, ln = l & 15;
    const int cw = wv % NCW, g = wv / NCW;

    int b = blockIdx.x;
    constexpr int TILES = 64 / (2 * G);
    const int tile = b % TILES;  b /= TILES;
    const int n = b;
    const int OY0 = tile * (2 * G);
    const int pc = (OUTM == 2) ? blockIdx.y : 0;

    // chunk-invariant staging geometry
    bool valid[SLOTS], okm[SLOTS];
    int goff[SLOTS], loff[SLOTS];
#pragma unroll
    for (int s = 0; s < SLOTS; s++) {
        const int idx = s * 512 + tid;
        valid[s] = idx < TASKS;
        const int q = idx & 3, cc = (idx >> 2) % 68, r = (idx >> 2) / 68;
        const int gr = OY0 - 1 + r, gx = cc - 1;
        okm[s] = valid[s] && gr >= 0 && gr < 64 && gx >= 0 && gx < 64;
        goff[s] = okm[s] ? ((gr * 64 + gx) * CI + 8 * q) : 0;
        loff[s] = (r * 68 + cc) * 40 + 8 * q;
    }

    f32x4 acc[2][8];
#pragma unroll
    for (int u = 0; u < 2; u++)
#pragma unroll
        for (int t = 0; t < 8; t++) acc[u][t] = (f32x4){0.f, 0.f, 0.f, 0.f};

    const u16* xn = x + (size_t)n * NP * CI * 4096;
    const int co0 = cw * 32 + ln;
    const short8 z8 = (short8){0, 0, 0, 0, 0, 0, 0, 0};

    short8 pf[SLOTS];
    // prologue: load chunk 0
    {
        const u16* xp = xn;           // plane 0, ci0 = 0
#pragma unroll
        for (int s = 0; s < SLOTS; s++)
            pf[s] = okm[s] ? *(const short8*)(xp + goff[s]) : z8;
    }

    for (int c = 0; c < NCHUNK; c++) {
        __syncthreads();
#pragma unroll
        for (int s = 0; s < SLOTS; s++)
            if (valid[s]) *(short8*)(XL + loff[s]) = pf[s];
        __syncthreads();

        // issue next chunk's loads (drain under MFMA)
        if (c + 1 < NCHUNK) {
            const int cn_ = c + 1;
            const u16* xp = xn + (size_t)(cn_ / CHP) * CI * 4096
                            + (cn_ % CHP) * 32;
#pragma unroll
            for (int s = 0; s < SLOTS; s++)
                pf[s] = okm[s] ? *(const short8*)(xp + goff[s]) : z8;
        }

        // compute chunk c
        const int p = c / CHP;
        const int ci0 = (c % CHP) * 32;
        int dy0, dx0;
        const u16* wgp;
        if (OUTM == 2) {
            dy0 = (pc >> 1) - 1; dx0 = (pc & 1) - 1;
            wgp = wg + (size_t)pc * J * I * COUT * CI;
        } else if (NP == 4) {
            dy0 = -(p >> 1); dx0 = -(p & 1);
            wgp = wg + (size_t)p * J * I * COUT * CI;
        } else {
            dy0 = -1; dx0 = -1; wgp = wg;
        }

#define TAP_ROW(jv)                                                          \
        {                                                                    \
            short8 wf0[I], wf1[I];                                           \
            _Pragma("unroll")                                                \
            for (int i = 0; i < I; i++) {                                    \
                const size_t wb = ((size_t)((jv) * I + i) * COUT + co0)      \
                                  * CI + ci0 + 8 * kg;                       \
                wf0[i] = *(const short8*)(wgp + wb);                         \
                wf1[i] = *(const short8*)(wgp + wb + (size_t)16 * CI);       \
            }                                                                \
            _Pragma("unroll")                                                \
            for (int i = 0; i < I; i++) {                                    \
                _Pragma("unroll")                                            \
                for (int t = 0; t < 8; t++) {                                \
                    const int rf = (t >> 2) + 2 * g + dy0 + 1 + (jv);        \
                    const int cf = (t & 3) * 16 + ln + dx0 + 1 + i;          \
                    const short8 bf = *(const short8*)(                      \
                        XL + (rf * 68 + cf) * 40 + 8 * kg);                  \
                    acc[0][t] = __builtin_amdgcn_mfma_f32_16x16x32_bf16(     \
                        wf0[i], bf, acc[0][t], 0, 0, 0);                     \
                    acc[1][t] = __builtin_amdgcn_mfma_f32_16x16x32_bf16(     \
                        wf1[i], bf, acc[1][t], 0, 0, 0);                     \
                }                                                            \
            }                                                                \
        }

        if constexpr (J == 2) {
            TAP_ROW(0); TAP_ROW(1);
        } else {
            TAP_ROW(0); TAP_ROW(1); TAP_ROW(2);
        }
#undef TAP_ROW
    }

#pragma unroll
    for (int u = 0; u < 2; u++) {
        const int cob = cw * 32 + u * 16 + 4 * kg;
#pragma unroll
        for (int t = 0; t < 8; t++) {
            const int oy = OY0 + 2 * g + (t >> 2);
            const int ox = (t & 3) * 16 + ln;
            if constexpr (OUTM == 1) {
                float* out = (float*)yv;
#pragma unroll
                for (int rr = 0; rr < 4; rr++)
                    out[(((size_t)n * COUT + cob + rr) * 64 + oy) * 64 + ox]
                        = acc[u][t][rr] + bias[cob + rr];
            } else {
                u16 pk[4];
#pragma unroll
                for (int rr = 0; rr < 4; rr++)
                    pk[rr] = f2bf(fmaxf(acc[u][t][rr] + bias[cob + rr], 0.f));
                if constexpr (OUTM == 0) {
                    *(u64*)((u16*)yv + ((size_t)(n * 64 + oy) * 64 + ox) * COUT
                            + cob) = *(const u64*)pk;
                } else {
                    const int OY = 2 * oy + (pc >> 1), OX = 2 * ox + (pc & 1);
                    *(u64*)((u16*)yv + ((size_t)(n * 128 + OY) * 128 + OX) * 128
                            + cob) = *(const u64*)pk;
                }
            }
        }
    }
}

// ---------------------------------------------------------------------------
// dec3m (R8, validated): deconv3 via parity-packed MFMA.
// ---------------------------------------------------------------------------
__global__ __launch_bounds__(256) void dec3m_k(
    const u16* __restrict__ A2, const u16* __restrict__ wg,
    const float* __restrict__ bias, float* __restrict__ out)
{
    const int tid = threadIdx.x;
    const int l = tid & 63, wvi = tid >> 6;
    const int ln = l & 15, kg = l >> 4;

    int b = blockIdx.x;
    const int mxT = b & 7;  b >>= 3;
    const int myT = b & 3;  b >>= 2;
    const int n = b;
    const int X0 = mxT * 16;
    const int MY0 = myT * 32 + wvi * 8;
    const int xx = X0 + ln;

    const short8 z8 = (short8){0, 0, 0, 0, 0, 0, 0, 0};

    f32x4 acc[8];
#pragma unroll
    for (int m = 0; m < 8; m++) acc[m] = (f32x4){0.f, 0.f, 0.f, 0.f};

    int xoff[3]; bool xok[3];
#pragma unroll
    for (int sh = 0; sh < 3; sh++) {
        const int xv = xx + sh - 1;
        xok[sh] = (xv >= 0) & (xv < 128);
        xoff[sh] = (xok[sh] ? xv : 0) << 7;
    }

    for (int ks = 0; ks < 4; ks++) {
        const int cio = ks * 32 + 8 * kg;

        short8 at[9];
#pragma unroll
        for (int t = 0; t < 9; t++)
            at[t] = *(const short8*)(wg + (((size_t)t * 16 + ln) << 7) + cio);

        short8 B[10][3];
#pragma unroll
        for (int r = 0; r < 10; r++) {
            const int yy = MY0 - 1 + r;
            const bool yok = (yy >= 0) & (yy < 128);
            const size_t rowb = ((size_t)(n * 128 + (yok ? yy : 0)) << 7 << 7);
#pragma unroll
            for (int sh = 0; sh < 3; sh++) {
                short8 v = *(const short8*)(A2 + rowb + xoff[sh] + cio);
                B[r][sh] = (yok & xok[sh]) ? v : z8;
            }
            if (r >= 2) {
                const int m = r - 2;
#pragma unroll
                for (int rr = 0; rr < 3; rr++)
#pragma unroll
                    for (int sh = 0; sh < 3; sh++)
                        acc[m] = __builtin_amdgcn_mfma_f32_16x16x32_bf16(
                            at[rr * 3 + sh], B[m + rr][sh], acc[m], 0, 0, 0);
            }
        }
    }

    if (kg < 3) {
#pragma unroll
        for (int m = 0; m < 8; m++) {
            const int my = MY0 + m;
#pragma unroll
            for (int rr = 0; rr < 4; rr++) {
                const int row = 4 * kg + rr;
                const int p = row / 3, co = row % 3;
                const int oy = 2 * my + (p >> 1);
                const int ox = 2 * xx + (p & 1);
                out[(((size_t)(n * 3 + co)) << 16) + oy * 256 + ox]
                    = acc[m][rr] + bias[co];
            }
        }
    }
}

// ---------------------------------------------------------------------------
// VQ via MFMA GEMM (R5, validated).
// ---------------------------------------------------------------------------
__global__ __launch_bounds__(256) void vqm_k(
    const float* __restrict__ ze, const u16* __restrict__ cb,
    const float* __restrict__ cn, const float* __restrict__ cbk,
    float* __restrict__ zq)
{
    __shared__ float CN[512];
    __shared__ int IDX[64];
    const int tid = threadIdx.x;
    const int l = tid & 63, wvi = tid >> 6;
    const int ln = l & 15, kg = l >> 4;

    for (int i = tid; i < 512; i += 256) CN[i] = cn[i];
    __syncthreads();

    const int V0 = blockIdx.x * 64 + wvi * 16;

    short8 az[2];
#pragma unroll
    for (int ks = 0; ks < 2; ks++) {
        const float* zp = ze + (size_t)(V0 + ln) * 64 + ks * 32 + 8 * kg;
        short8 t;
#pragma unroll
        for (int j = 0; j < 8; j++) t[j] = (short)f2bf(zp[j]);
        az[ks] = t;
    }

    float bval[4] = {3.4e38f, 3.4e38f, 3.4e38f, 3.4e38f};
    int bidx[4] = {0, 0, 0, 0};
    for (int nt = 0; nt < 32; nt++) {
        const int code = nt * 16 + ln;
        const short8 b0 = *(const short8*)(cb + (size_t)code * 64 + 8 * kg);
        const short8 b1 = *(const short8*)(cb + (size_t)code * 64 + 32 + 8 * kg);
        f32x4 d = (f32x4){0.f, 0.f, 0.f, 0.f};
        d = __builtin_amdgcn_mfma_f32_16x16x32_bf16(az[0], b0, d, 0, 0, 0);
        d = __builtin_amdgcn_mfma_f32_16x16x32_bf16(az[1], b1, d, 0, 0, 0);
        const float cnv = CN[code];
#pragma unroll
        for (int r = 0; r < 4; r++) {
            const float dist = cnv - 2.f * d[r];
            if (dist < bval[r]) { bval[r] = dist; bidx[r] = code; }
        }
    }
#pragma unroll
    for (int off = 1; off < 16; off <<= 1) {
#pragma unroll
        for (int r = 0; r < 4; r++) {
            const float ov = __shfl_xor(bval[r], off);
            const int oi = __shfl_xor(bidx[r], off);
            if (ov < bval[r] || (ov == bval[r] && oi < bidx[r])) {
                bval[r] = ov; bidx[r] = oi;
            }
        }
    }
    if (ln == 0) {
#pragma unroll
        for (int r = 0; r < 4; r++) IDX[wvi * 16 + 4 * kg + r] = bidx[r];
    }
    __syncthreads();

    const int vs = tid >> 2, ch = tid & 3;
    const int bi = IDX[vs];
    const float4* sp = (const float4*)(cbk + (size_t)bi * 64 + ch * 16);
    float4* dp = (float4*)(zq + ((size_t)blockIdx.x * 64 + vs) * 64 + ch * 16);
#pragma unroll
    for (int q = 0; q < 4; q++) dp[q] = sp[q];
}

// zq (fp32 NCHW) -> channel-last bf16 [n][y][x][64]
__global__ __launch_bounds__(256) void zqt_k(
    const float* __restrict__ zq, u16* __restrict__ out)
{
    __shared__ float t[64][65];
    const int tid = threadIdx.x;
    const int n = blockIdx.x >> 6, y = blockIdx.x & 63;
    for (int idx = tid; idx < 4096; idx += 256) {
        int xx = idx & 63, ci = idx >> 6;
        t[ci][xx] = zq[(((size_t)n * 64 + ci) * 64 + y) * 64 + xx];
    }
    __syncthreads();
    for (int idx = tid; idx < 4096; idx += 256) {
        int ci = idx & 63, xx = idx >> 6;
        out[(((size_t)n * 64 + y) * 64 + xx) * 64 + ci] = f2bf(t[ci][xx]);
    }
}

// ---------------------------------------------------------------------------
extern "C" void kernel_launch(void* const* d_in, const int* in_sizes, int n_in,
                              void* d_out, int out_size, void* d_ws, size_t ws_size,
                              hipStream_t stream)
{
    (void)in_sizes; (void)n_in; (void)out_size; (void)ws_size;

    const float* x   = (const float*)d_in[0];
    const float* ew1 = (const float*)d_in[1];
    const float* eb1 = (const float*)d_in[2];
    const float* ew2 = (const float*)d_in[3];
    const float* eb2 = (const float*)d_in[4];
    const float* ew3 = (const float*)d_in[5];
    const float* eb3 = (const float*)d_in[6];
    const float* cbk = (const float*)d_in[7];
    const float* dw1 = (const float*)d_in[8];
    const float* db1 = (const float*)d_in[9];
    const float* dw2 = (const float*)d_in[10];
    const float* db2 = (const float*)d_in[11];
    const float* dw3 = (const float*)d_in[12];
    const float* db3 = (const float*)d_in[13];

    u16* P    = (u16*)d_ws;
    u16* ZQCL = P;
    u16* A2   = P;
    u16* B = (u16*)((char*)d_ws + 134217728);
    u16* XCL = B;
    u16* Wg2 = (u16*)((char*)d_ws + 167772160);       // 262144
    u16* Wg3 = Wg2 + 262144;                          // 73728
    u16* Wg4 = Wg3 + 73728;                           // 73728
    u16* Wg5 = Wg4 + 73728;                           // 262144
    u16* Wg6 = Wg5 + 262144;                          // 18432 (dec3m)
    u16* CB  = Wg6 + 32768;                           // 32768
    u16* Wg1 = CB + 32768;                            // 8192
    float* CNg = (float*)(Wg1 + 8192);                // 512

    float* xr = (float*)d_out;
    float* ze = xr + (size_t)32 * 3 * 256 * 256;
    float* zq = ze + (size_t)32 * 64 * 64 * 64;

    g_enc1<<<32, 256, 0, stream>>>(ew1, Wg1);
    g_enc2<<<1024, 256, 0, stream>>>(ew2, Wg2);
    g_k3<<<288, 256, 0, stream>>>(ew3, Wg3, 128, 64);
    g_k3<<<288, 256, 0, stream>>>(dw1, Wg4, 64, 128);
    g_dec2<<<1024, 256, 0, stream>>>(dw2, Wg5);
    g_dec3m<<<72, 256, 0, stream>>>(dw3, Wg6);
    g_cbk<<<128, 256, 0, stream>>>(cbk, CB, CNg);

    xcl_k<<<32 * 258, 256, 0, stream>>>(x, XCL);
    enc1m_k<<<32 * 128, 256, 0, stream>>>(XCL, Wg1, eb1, P);
    // enc2: 4 planes k2 -> B (CL, relu). NCW=4, G=2 (4 rows/block), 16 tiles.
    conv_mx3<2, 2, 4, 4, 128, 0><<<32 * 16, 512, 0, stream>>>(P, Wg2, eb2, B, 128);
    // enc3: k3 -> ze (fp32). COUT=64: NCW=2, G=4 (8 rows/block), 8 tiles.
    conv_mx3<3, 3, 1, 2, 128, 1><<<32 * 8, 512, 0, stream>>>(B, Wg3, eb3, ze, 64);
    // VQ
    vqm_k<<<2048, 256, 0, stream>>>(ze, CB, CNg, cbk, zq);
    zqt_k<<<2048, 256, 0, stream>>>(zq, ZQCL);
    // dec1: k3 -> B (CL, relu). CIN=64.
    conv_mx3<3, 3, 1, 4, 64, 0><<<32 * 16, 512, 0, stream>>>(ZQCL, Wg4, db1, B, 128);
    // deconv2: k2 x 4 parities -> A2 (CL, relu)
    conv_mx3<2, 2, 1, 4, 128, 2><<<dim3(32 * 16, 4), 512, 0, stream>>>(B, Wg5, db2, A2, 128);
    // deconv3 -> x_recon
    dec3m_k<<<1024, 256, 0, stream>>>(A2, Wg6, db3, xr);
}